// Round 5
// baseline (2846.245 us; speedup 1.0000x reference)
//
#include <hip/hip_runtime.h>
#include <cstdint>
#include <cmath>

#define MASKV -9.0e20f

// ---------------- Threefry-2x32 (JAX-compatible) ----------------
__host__ __device__ inline void tf2x32(uint32_t k0, uint32_t k1, uint32_t& x0, uint32_t& x1){
  uint32_t ks2 = k0 ^ k1 ^ 0x1BD11BDAu;
  x0 += k0; x1 += k1;
#define TFR(r) { x0 += x1; x1 = (x1<<(r))|(x1>>(32-(r))); x1 ^= x0; }
  TFR(13) TFR(15) TFR(26) TFR(6)
  x0 += k1;  x1 += ks2 + 1u;
  TFR(17) TFR(29) TFR(16) TFR(24)
  x0 += ks2; x1 += k0 + 2u;
  TFR(13) TFR(15) TFR(26) TFR(6)
  x0 += k0;  x1 += k1 + 3u;
  TFR(17) TFR(29) TFR(16) TFR(24)
  x0 += k1;  x1 += ks2 + 4u;
  TFR(13) TFR(15) TFR(26) TFR(6)
  x0 += ks2; x1 += k0 + 5u;
#undef TFR
}

__device__ inline uint32_t rbits32(uint32_t k0, uint32_t k1, uint32_t idx){
  uint32_t x0 = 0u, x1 = idx;
  tf2x32(k0, k1, x0, x1);
  return x0 ^ x1;
}

__device__ inline float u01_from_bits(uint32_t bits){
  union { uint32_t u; float f; } c;
  c.u = (bits >> 9) | 0x3f800000u;
  return c.f - 1.0f;
}

__device__ inline float erfinv_f(float x){
  float w = -log1pf(-x*x);
  float p;
  if (w < 5.0f){
    w -= 2.5f;
    p = 2.81022636e-08f;
    p = fmaf(p, w, 3.43273939e-07f);
    p = fmaf(p, w, -3.5233877e-06f);
    p = fmaf(p, w, -4.39150654e-06f);
    p = fmaf(p, w, 0.00021858087f);
    p = fmaf(p, w, -0.00125372503f);
    p = fmaf(p, w, -0.00417768164f);
    p = fmaf(p, w, 0.246640727f);
    p = fmaf(p, w, 1.50140941f);
  } else {
    w = sqrtf(w) - 3.0f;
    p = -0.000200214257f;
    p = fmaf(p, w, 0.000100950558f);
    p = fmaf(p, w, 0.00134934322f);
    p = fmaf(p, w, -0.00367342844f);
    p = fmaf(p, w, 0.00573950773f);
    p = fmaf(p, w, -0.0076224613f);
    p = fmaf(p, w, 0.00943887047f);
    p = fmaf(p, w, 1.00167406f);
    p = fmaf(p, w, 2.83297682f);
  }
  return p * x;
}

__device__ inline float jax_normal(uint32_t k0, uint32_t k1, uint32_t idx){
  float f = u01_from_bits(rbits32(k0, k1, idx));
  float v = fmaf(f, 2.0f, -0.99999994f);
  v = fmaxf(v, -0.99999994f);
  return 1.41421356f * erfinv_f(v);
}

__device__ inline float jax_gumbel(uint32_t k0, uint32_t k1, uint32_t idx){
  float f = u01_from_bits(rbits32(k0, k1, idx));
  f = f + 1.17549435e-38f;
  f = fmaxf(f, 1.17549435e-38f);
  return -logf(-logf(f));
}

// ---------------- small tiled SGEMM (64x64 tile, 4x4 microtile) ----------------
template<int ACT>
__global__ __launch_bounds__(256) void gemm_k(
    const float* __restrict__ A, int lda,
    const long* __restrict__ atab, int anblk,
    const float* __restrict__ W, const float* __restrict__ bias,
    float* __restrict__ C, int K, int N,
    long c_base, int c_rdiv, long c_ostride, long c_istride)
{
  __shared__ float As[16][64];
  __shared__ float Ws[16][64];
  int tid = threadIdx.x;
  int c0 = blockIdx.x * 64;
  int r0 = blockIdx.y * 64;
  int lr = tid >> 2;
  int lk = (tid & 3) << 2;
  int wk = tid >> 4;
  int wc = (tid & 15) << 2;
  int tx = tid & 15;
  int ty = tid >> 4;
  long aoff0 = 0, aoff1 = 0;
  if (atab){
    const long* t = atab + (long)(r0 + lr) * anblk;
    aoff0 = t[0];
    if (anblk == 2) aoff1 = t[1];
  } else {
    aoff0 = (long)(r0 + lr) * lda;
  }
  float acc[4][4];
#pragma unroll
  for (int i = 0; i < 4; i++)
#pragma unroll
    for (int j = 0; j < 4; j++) acc[i][j] = 0.f;

  for (int k0 = 0; k0 < K; k0 += 16){
    int ka = k0 + lk;
    long ab = (atab && anblk == 2 && ka >= 512) ? (aoff1 + (ka - 512)) : (aoff0 + ka);
    float4 av = *(const float4*)(A + ab);
    As[lk + 0][lr] = av.x;
    As[lk + 1][lr] = av.y;
    As[lk + 2][lr] = av.z;
    As[lk + 3][lr] = av.w;
    float4 wv = *(const float4*)(W + (long)(k0 + wk) * N + (c0 + wc));
    *(float4*)&Ws[wk][wc] = wv;
    __syncthreads();
#pragma unroll
    for (int kk = 0; kk < 16; kk++){
      float4 a4 = *(const float4*)&As[kk][ty << 2];
      float4 w4 = *(const float4*)&Ws[kk][tx << 2];
      float aa[4] = {a4.x, a4.y, a4.z, a4.w};
      float ww[4] = {w4.x, w4.y, w4.z, w4.w};
#pragma unroll
      for (int i = 0; i < 4; i++)
#pragma unroll
        for (int j = 0; j < 4; j++)
          acc[i][j] = fmaf(aa[i], ww[j], acc[i][j]);
    }
    __syncthreads();
  }
  float4 bv = *(const float4*)(bias + c0 + (tx << 2));
  float bb[4] = {bv.x, bv.y, bv.z, bv.w};
#pragma unroll
  for (int i = 0; i < 4; i++){
    int r = r0 + (ty << 2) + i;
    long off = c_base + (long)(r / c_rdiv) * c_ostride + (long)(r % c_rdiv) * c_istride
               + c0 + (tx << 2);
    float4 v;
    float o0 = acc[i][0] + bb[0], o1 = acc[i][1] + bb[1];
    float o2 = acc[i][2] + bb[2], o3 = acc[i][3] + bb[3];
    if (ACT){ o0 = fmaxf(o0, 0.f); o1 = fmaxf(o1, 0.f); o2 = fmaxf(o2, 0.f); o3 = fmaxf(o3, 0.f); }
    v.x = o0; v.y = o1; v.z = o2; v.w = o3;
    *(float4*)(C + off) = v;
  }
}

// ---------------- 128-tile fused policy GEMM (initial step, 30720 rows) ----------------
// microtile = 2x(4 rows) x 2x(4 cols), halves 64 apart -> conflict-free LDS reads
__global__ __launch_bounds__(256) void gemm128f_k(
    const float* __restrict__ Y,
    const long* __restrict__ atab,
    const float* __restrict__ b1,
    const float* __restrict__ W2, const float* __restrict__ b2,
    const float* __restrict__ w3,
    const int* __restrict__ scat, float* __restrict__ logits)
{
  __shared__ float As[16][132];
  __shared__ float Ws[16][132];
  int tid = threadIdx.x;
  int c0 = blockIdx.x * 128;
  int r0 = blockIdx.y * 128;
  int tx = tid & 15, ty = tid >> 4;
  int rA0 = tid >> 2;
  int rA1 = rA0 + 64;
  int kq = (tid & 3) << 2;
  long a00 = atab[(long)(r0 + rA0) * 2];
  long a01 = atab[(long)(r0 + rA0) * 2 + 1];
  long a10 = atab[(long)(r0 + rA1) * 2];
  long a11 = atab[(long)(r0 + rA1) * 2 + 1];
  int wk0 = tid >> 5, wc0 = (tid & 31) << 2;
  float acc[8][8];
#pragma unroll
  for (int i = 0; i < 8; i++)
#pragma unroll
    for (int j = 0; j < 8; j++) acc[i][j] = 0.f;

  for (int k0 = 0; k0 < 512; k0 += 16){
    int ka = k0 + kq;
    float4 p0 = *(const float4*)(Y + a00 + ka);
    float4 q0 = *(const float4*)(Y + a01 + ka);
    float4 p1 = *(const float4*)(Y + a10 + ka);
    float4 q1 = *(const float4*)(Y + a11 + ka);
    float4 bb = *(const float4*)(b1 + ka);
    As[kq + 0][rA0] = fmaxf(p0.x + q0.x + bb.x, 0.f);
    As[kq + 1][rA0] = fmaxf(p0.y + q0.y + bb.y, 0.f);
    As[kq + 2][rA0] = fmaxf(p0.z + q0.z + bb.z, 0.f);
    As[kq + 3][rA0] = fmaxf(p0.w + q0.w + bb.w, 0.f);
    As[kq + 0][rA1] = fmaxf(p1.x + q1.x + bb.x, 0.f);
    As[kq + 1][rA1] = fmaxf(p1.y + q1.y + bb.y, 0.f);
    As[kq + 2][rA1] = fmaxf(p1.z + q1.z + bb.z, 0.f);
    As[kq + 3][rA1] = fmaxf(p1.w + q1.w + bb.w, 0.f);
    *(float4*)&Ws[wk0][wc0]     = *(const float4*)(W2 + (long)(k0 + wk0) * 512 + (c0 + wc0));
    *(float4*)&Ws[wk0 + 8][wc0] = *(const float4*)(W2 + (long)(k0 + wk0 + 8) * 512 + (c0 + wc0));
    __syncthreads();
#pragma unroll
    for (int kk = 0; kk < 16; kk++){
      float a0[8], w0[8];
      *(float4*)&a0[0] = *(const float4*)&As[kk][ty << 2];
      *(float4*)&a0[4] = *(const float4*)&As[kk][(ty << 2) + 64];
      *(float4*)&w0[0] = *(const float4*)&Ws[kk][tx << 2];
      *(float4*)&w0[4] = *(const float4*)&Ws[kk][(tx << 2) + 64];
#pragma unroll
      for (int i = 0; i < 8; i++)
#pragma unroll
        for (int j = 0; j < 8; j++)
          acc[i][j] = fmaf(a0[i], w0[j], acc[i][j]);
    }
    __syncthreads();
  }
  float bb[8], w3v[8];
  *(float4*)&bb[0]  = *(const float4*)(b2 + c0 + (tx << 2));
  *(float4*)&bb[4]  = *(const float4*)(b2 + c0 + (tx << 2) + 64);
  *(float4*)&w3v[0] = *(const float4*)(w3 + c0 + (tx << 2));
  *(float4*)&w3v[4] = *(const float4*)(w3 + c0 + (tx << 2) + 64);
#pragma unroll
  for (int i = 0; i < 8; i++){
    float p = 0.f;
#pragma unroll
    for (int j = 0; j < 8; j++)
      p = fmaf(fmaxf(acc[i][j] + bb[j], 0.f), w3v[j], p);
    for (int m = 1; m < 16; m <<= 1) p += __shfl_xor(p, m);
    if (tx == 0){
      int rr = (i < 4) ? ((ty << 2) + i) : (64 + (ty << 2) + (i - 4));
      atomicAdd(logits + scat[r0 + rr], p);
    }
  }
}

// ---------------- 64-tile fused policy GEMM (in-loop, rows <= 3584) ----------------
__global__ __launch_bounds__(256) void gemm64f_k(
    const float* __restrict__ Y,
    const long* __restrict__ atab,
    const float* __restrict__ b1,
    const float* __restrict__ W2, const float* __restrict__ b2,
    const float* __restrict__ w3,
    const int* __restrict__ scat, float* __restrict__ logits)
{
  __shared__ float As[16][64];
  __shared__ float Ws[16][64];
  int tid = threadIdx.x;
  int c0 = blockIdx.x * 64;
  int r0 = blockIdx.y * 64;
  int lr = tid >> 2;
  int lk = (tid & 3) << 2;
  int wk = tid >> 4;
  int wc = (tid & 15) << 2;
  int tx = tid & 15;
  int ty = tid >> 4;
  long a0 = atab[(long)(r0 + lr) * 2];
  long a1 = atab[(long)(r0 + lr) * 2 + 1];
  float acc[4][4];
#pragma unroll
  for (int i = 0; i < 4; i++)
#pragma unroll
    for (int j = 0; j < 4; j++) acc[i][j] = 0.f;

  for (int k0 = 0; k0 < 512; k0 += 16){
    int ka = k0 + lk;
    float4 p = *(const float4*)(Y + a0 + ka);
    float4 q = *(const float4*)(Y + a1 + ka);
    float4 bb = *(const float4*)(b1 + ka);
    As[lk + 0][lr] = fmaxf(p.x + q.x + bb.x, 0.f);
    As[lk + 1][lr] = fmaxf(p.y + q.y + bb.y, 0.f);
    As[lk + 2][lr] = fmaxf(p.z + q.z + bb.z, 0.f);
    As[lk + 3][lr] = fmaxf(p.w + q.w + bb.w, 0.f);
    *(float4*)&Ws[wk][wc] = *(const float4*)(W2 + (long)(k0 + wk) * 512 + (c0 + wc));
    __syncthreads();
#pragma unroll
    for (int kk = 0; kk < 16; kk++){
      float4 a4 = *(const float4*)&As[kk][ty << 2];
      float4 w4 = *(const float4*)&Ws[kk][tx << 2];
      float aa[4] = {a4.x, a4.y, a4.z, a4.w};
      float ww[4] = {w4.x, w4.y, w4.z, w4.w};
#pragma unroll
      for (int i = 0; i < 4; i++)
#pragma unroll
        for (int j = 0; j < 4; j++)
          acc[i][j] = fmaf(aa[i], ww[j], acc[i][j]);
    }
    __syncthreads();
  }
  float bb4[4], w34[4];
  *(float4*)&bb4[0] = *(const float4*)(b2 + c0 + (tx << 2));
  *(float4*)&w34[0] = *(const float4*)(w3 + c0 + (tx << 2));
#pragma unroll
  for (int i = 0; i < 4; i++){
    float p = 0.f;
#pragma unroll
    for (int j = 0; j < 4; j++)
      p = fmaf(fmaxf(acc[i][j] + bb4[j], 0.f), w34[j], p);
    for (int m = 1; m < 16; m <<= 1) p += __shfl_xor(p, m);
    if (tx == 0){
      int r = r0 + (ty << 2) + i;
      atomicAdd(logits + scat[r], p);
    }
  }
}

// N=2 final layer: one wave per row
__global__ __launch_bounds__(256) void rowdot_k(
    const float* __restrict__ A, int lda,
    const float* __restrict__ W, const float* __restrict__ bias,
    int K, float* __restrict__ out,
    long c_base, int c_rdiv, long c_ostride, long c_istride)
{
  int wid = threadIdx.x >> 6, lane = threadIdx.x & 63;
  int r = blockIdx.x * 4 + wid;
  const float* a = A + (long)r * lda;
  float s0 = 0.f, s1 = 0.f;
  for (int k = lane; k < K; k += 64){
    float x = a[k];
    s0 = fmaf(x, W[k * 2], s0);
    s1 = fmaf(x, W[k * 2 + 1], s1);
  }
  for (int off = 32; off > 0; off >>= 1){
    s0 += __shfl_down(s0, off);
    s1 += __shfl_down(s1, off);
  }
  if (lane == 0){
    long o = c_base + (long)(r / c_rdiv) * c_ostride + (long)(r % c_rdiv) * c_istride;
    out[o] = s0 + bias[0];
    out[o + 1] = s1 + bias[1];
  }
}

// ---------------- 1024-thread 2-K-slice matvec layer (src/dst in LDS) ----------------
__device__ inline void mlayer(const float* __restrict__ W, const float* __restrict__ bias,
    const float* src, float* dst, float (*ps)[512], int Khalf, int relu, int tid)
{
  int c = tid & 511, ks = tid >> 9;
  int kb = ks * Khalf;
  float a0 = 0.f, a1 = 0.f, a2 = 0.f, a3 = 0.f;
#pragma unroll 8
  for (int k = kb; k < kb + Khalf; k += 4){
    a0 = fmaf(src[k],     W[(long)k * 512 + c],       a0);
    a1 = fmaf(src[k + 1], W[(long)(k + 1) * 512 + c], a1);
    a2 = fmaf(src[k + 2], W[(long)(k + 2) * 512 + c], a2);
    a3 = fmaf(src[k + 3], W[(long)(k + 3) * 512 + c], a3);
  }
  ps[ks][c] = (a0 + a1) + (a2 + a3);
  __syncthreads();
  if (tid < 512){
    float v = ps[0][tid] + ps[1][tid] + bias[tid];
    dst[tid] = relu ? fmaxf(v, 0.f) : v;
  }
  __syncthreads();
}

// ---------------- fused sample + enc + u-append + Y-row: one block per batch row ----------------
__global__ __launch_bounds__(1024) void sampenc_k(
    float* __restrict__ logits, int* __restrict__ active,
    int* __restrict__ actions, float* __restrict__ lp, float* __restrict__ ent,
    float* __restrict__ u, float* __restrict__ Y, float* __restrict__ z_all,
    const float* __restrict__ ew1, const float* __restrict__ eb1,
    const float* __restrict__ ew2, const float* __restrict__ eb2,
    const float* __restrict__ ew3, const float* __restrict__ eb3,
    const float* __restrict__ W1cat,
    long* __restrict__ tab_loop, int* __restrict__ scat_loop,
    const float* __restrict__ pol_b3,
    int it, int A, uint32_t ck0, uint32_t ck1, uint32_t mk0, uint32_t mk1, float log_opt)
{
  int b = blockIdx.x, tid = threadIdx.x;
  float* Lg = logits + (long)b * 900;
  __shared__ float red[1024];
  __shared__ int redi[1024];
  __shared__ float sIn[1024];
  __shared__ float ps[2][512];
  __shared__ float hA[512], hB[512];
  __shared__ int ss0, ss1;

  // ---- softmax stats (one element per thread) ----
  float l = (tid < 900) ? Lg[tid] : -3.4e38f;
  red[tid] = l; __syncthreads();
  for (int s = 512; s > 0; s >>= 1){ if (tid < s) red[tid] = fmaxf(red[tid], red[tid + s]); __syncthreads(); }
  float m = red[0]; __syncthreads();
  float e = (tid < 900) ? expf(l - m) : 0.f;
  red[tid] = e; __syncthreads();
  for (int s = 512; s > 0; s >>= 1){ if (tid < s) red[tid] += red[tid + s]; __syncthreads(); }
  float ssum = red[0]; __syncthreads();
  float es = 0.f;
  if (tid < 900 && l > MASKV){
    float p = e / ssum;
    float pa = p + 1e-20f;
    es = pa * logf(pa);
  }
  red[tid] = es; __syncthreads();
  for (int s = 512; s > 0; s >>= 1){ if (tid < s) red[tid] += red[tid + s]; __syncthreads(); }
  if (tid == 0) ent[b] += -(red[0]) / log_opt;
  __syncthreads();

  // ---- gumbel argmax ----
  float g = (tid < 900) ? (l + jax_gumbel(ck0, ck1, (uint32_t)(b * 900 + tid))) : -3.4e38f;
  red[tid] = g; redi[tid] = tid; __syncthreads();
  for (int s = 512; s > 0; s >>= 1){
    if (tid < s){
      float o = red[tid + s]; int oi = redi[tid + s];
      if (o > red[tid] || (o == red[tid] && oi < redi[tid])){ red[tid] = o; redi[tid] = oi; }
    }
    __syncthreads();
  }
  if (tid == 0){
    int sf = redi[0];
    int s0 = sf / 30, s1 = sf % 30;
    ss0 = s0; ss1 = s1;
    actions[(b * 15 + it) * 2] = s0;
    actions[(b * 15 + it) * 2 + 1] = s1;
    lp[b * 15 + it] = Lg[sf] - m - logf(ssum);
  }
  __syncthreads();
  int s0 = ss0, s1 = ss1;
  if (tid < 30){
    Lg[s0 * 30 + tid] = MASKV;
    Lg[s1 * 30 + tid] = MASKV;
    Lg[tid * 30 + s0] = MASKV;
    Lg[tid * 30 + s1] = MASKV;
  }
  if (tid == 0){
    float b3v = pol_b3[0];
    int buf[16]; int c = 0;
    for (int k = 0; k < A; k++){
      int a = active[b * 16 + k];
      if (a != s0 && a != s1) buf[c++] = a;
    }
    int nt2 = 16 + it;
    buf[c++] = nt2;
    for (int k = 0; k < c; k++) active[b * 16 + k] = buf[k];
    int na2 = c - 1;
    for (int j = 0; j < na2; j++){
      int q = buf[j];
      int r1 = j * 128 + b;
      tab_loop[r1 * 2]     = ((long)(b * 31 + nt2)) * 1024;
      tab_loop[r1 * 2 + 1] = ((long)(b * 31 + q)) * 1024 + 512;
      int sc1 = b * 900 + nt2 * 30 + q;
      scat_loop[r1] = sc1;
      logits[sc1] = b3v;
      int r2 = (na2 + j) * 128 + b;
      tab_loop[r2 * 2]     = ((long)(b * 31 + q)) * 1024;
      tab_loop[r2 * 2 + 1] = ((long)(b * 31 + nt2)) * 1024 + 512;
      int sc2 = b * 900 + q * 30 + nt2;
      scat_loop[r2] = sc2;
      logits[sc2] = b3v;
    }
  }

  // ---- enc(pair) ----
  sIn[tid] = (tid < 512) ? u[((long)(b * 31 + s0)) * 512 + tid]
                         : u[((long)(b * 31 + s1)) * 512 + (tid - 512)];
  __syncthreads();
  mlayer(ew1, eb1, sIn, hA, ps, 512, 1, tid);   // K=1024
  mlayer(ew2, eb2, hA, hB, ps, 256, 1, tid);    // K=512
  mlayer(ew3, eb3, hB, hA, ps, 256, 0, tid);    // K=512, z in hA
  if (tid < 512){
    float z = hA[tid];
    z_all[(long)it * 65536 + (long)b * 512 + tid] = z;
    float uv = z + 0.01f * jax_normal(mk0, mk1, (uint32_t)(b * 512 + tid));
    u[((long)(b * 31 + 16 + it)) * 512 + tid] = uv;
    hB[tid] = uv;
  }
  __syncthreads();
  // ---- Y row for new token ----
  if (it < 14){
    float a0 = 0.f, a1 = 0.f, a2 = 0.f, a3 = 0.f;
#pragma unroll 8
    for (int k = 0; k < 512; k += 4){
      a0 = fmaf(hB[k],     W1cat[(long)k * 1024 + tid],       a0);
      a1 = fmaf(hB[k + 1], W1cat[(long)(k + 1) * 1024 + tid], a1);
      a2 = fmaf(hB[k + 2], W1cat[(long)(k + 2) * 1024 + tid], a2);
      a3 = fmaf(hB[k + 3], W1cat[(long)(k + 3) * 1024 + tid], a3);
    }
    Y[((long)(b * 31 + 16 + it)) * 1024 + tid] = (a0 + a1) + (a2 + a3);
  }
}

// ---------------- fused reverse step: dec chain + scatter (it=0 absorbs d-init) ----------------
__global__ __launch_bounds__(1024) void rev_k(
    float* __restrict__ dmat, const float* __restrict__ u,
    const int* __restrict__ actions,
    const float* __restrict__ dw1, const float* __restrict__ db1,
    const float* __restrict__ dw2, const float* __restrict__ db2,
    const float* __restrict__ dw3, const float* __restrict__ db3,
    int it)
{
  __shared__ float sA[512], sB[512];
  __shared__ float ps[2][512];
  int b = blockIdx.x, tid = threadIdx.x;
  int tok = 30 - it, fit = 14 - it;
  if (tid < 512){
    long off = ((long)(b * 31 + tok)) * 512 + tid;
    float v;
    if (it == 0){ v = u[off]; dmat[off] = v; }
    else v = dmat[off];
    sA[tid] = v;
  }
  __syncthreads();
  mlayer(dw1, db1, sA, sB, ps, 256, 1, tid);
  mlayer(dw2, db2, sB, sA, ps, 256, 1, tid);
  // dec3: C=1024, one col per thread
  float a0 = 0.f, a1 = 0.f, a2 = 0.f, a3 = 0.f;
#pragma unroll 8
  for (int k = 0; k < 512; k += 4){
    a0 = fmaf(sA[k],     dw3[(long)k * 1024 + tid],       a0);
    a1 = fmaf(sA[k + 1], dw3[(long)(k + 1) * 1024 + tid], a1);
    a2 = fmaf(sA[k + 2], dw3[(long)(k + 2) * 1024 + tid], a2);
    a3 = fmaf(sA[k + 3], dw3[(long)(k + 3) * 1024 + tid], a3);
  }
  float v = ((a0 + a1) + (a2 + a3)) + db3[tid];
  int s0 = actions[(b * 15 + fit) * 2];
  int s1 = actions[(b * 15 + fit) * 2 + 1];
  int node = (tid < 512) ? s0 : s1;
  dmat[((long)(b * 31 + node)) * 512 + (tid & 511)] = v;
}

// batched osl over all steps: grid 1920 (r = it*128 + b)
__global__ __launch_bounds__(256) void oslb_k(
    const float* __restrict__ pred, const float* __restrict__ u,
    const int* __restrict__ actions, float* __restrict__ sl, float* __restrict__ rew)
{
  int r = blockIdx.x, tid = threadIdx.x;
  int it = r >> 7, b = r & 127;
  int s0 = actions[(b * 15 + it) * 2];
  int s1 = actions[(b * 15 + it) * 2 + 1];
  const float* t0 = u + ((long)(b * 31 + s0)) * 512;
  const float* t1 = u + ((long)(b * 31 + s1)) * 512;
  const float* p = pred + (long)r * 1024;
  float s = 0.f;
  for (int k = tid; k < 512; k += 256){
    float d0 = p[k] - t0[k];       s = fmaf(d0, d0, s);
    float d1 = p[k + 512] - t1[k]; s = fmaf(d1, d1, s);
  }
  __shared__ float red[256];
  red[tid] = s; __syncthreads();
  for (int st = 128; st > 0; st >>= 1){ if (tid < st) red[tid] += red[tid + st]; __syncthreads(); }
  if (tid == 0){
    float osl = red[0] / 1024.0f;
    atomicAdd(sl + b, osl);
    rew[b * 15 + it] = -osl;
  }
}

// ---------------- init ----------------
__global__ __launch_bounds__(256) void init_k(float* __restrict__ dmat, float* __restrict__ lbl,
    float* __restrict__ logits, float* __restrict__ sl, float* __restrict__ ent,
    int* __restrict__ active, float* __restrict__ zb,
    float* __restrict__ W1cat, const float* __restrict__ pol_w1, const float* __restrict__ pol_b3,
    long* __restrict__ tab_init, int* __restrict__ scat_init, long* __restrict__ tab_tok16,
    long* __restrict__ tab_mgd)
{
  long i = (long)blockIdx.x * 256 + threadIdx.x;
  if (i < 2031616L) dmat[i] = 0.f;
  if (i < 524288L){
    int k = (int)(i >> 10), n = (int)(i & 1023);
    W1cat[i] = (n < 512) ? pol_w1[(long)k * 512 + n] : pol_w1[(long)(k + 512) * 512 + (n - 512)];
  }
  if (i < 115200L){
    int rem = (int)(i % 900);
    int rr = rem / 30, cc = rem % 30;
    logits[i] = (rr < 16 && cc < 16 && rr != cc) ? pol_b3[0] : MASKV;
  }
  if (i < 30720L){
    int r = (int)i;
    int pk = r >> 7, b = r & 127;
    int ii2 = pk / 15, jr = pk % 15;
    int jj2 = jr + (jr >= ii2 ? 1 : 0);
    tab_init[r * 2]     = ((long)(b * 31 + ii2)) * 1024;
    tab_init[r * 2 + 1] = ((long)(b * 31 + jj2)) * 1024 + 512;
    scat_init[r] = b * 900 + ii2 * 30 + jj2;
  }
  if (i < 3968L)  lbl[i] = ((i % 31) < 15) ? 1.0f : 0.0f;
  if (i < 2048L){
    active[i] = (int)(i & 15);
    tab_tok16[i] = ((long)((i >> 4) * 31 + (i & 15))) * 512;
  }
  if (i < 1920L){
    int it = (int)(i >> 7), b = (int)(i & 127);
    tab_mgd[i] = ((long)(b * 31 + 30 - it)) * 512;
  }
  if (i < 1024L)  zb[i] = 0.f;
  if (i < 128L){ sl[i] = 0.f; ent[i] = 0.f; }
}

__global__ __launch_bounds__(256) void noise_u_k(float* __restrict__ u, uint32_t k0, uint32_t k1){
  uint32_t e = blockIdx.x * 256u + threadIdx.x; // < 1048576
  uint32_t b = e >> 13, rem = e & 8191u, n = rem >> 9, ee = rem & 511u;
  float nr = jax_normal(k0, k1, e);
  long off = ((long)(b * 31u + n)) * 512 + ee;
  u[off] += 0.01f * nr;
}

__global__ __launch_bounds__(256) void finalize_k(const float* __restrict__ rew,
    const float* __restrict__ lp, const float* __restrict__ sl, const float* __restrict__ ent,
    float* __restrict__ out_sl, float* __restrict__ out_ent, float* __restrict__ out_reinf)
{
  __shared__ float red[256];
  int tid = threadIdx.x;
  float s = 0.f;
  for (int i = tid; i < 1920; i += 256) s += rew[i];
  red[tid] = s; __syncthreads();
  for (int st = 128; st > 0; st >>= 1){ if (tid < st) red[tid] += red[tid + st]; __syncthreads(); }
  float mean = red[0] / 1920.0f; __syncthreads();
  float v = 0.f;
  for (int i = tid; i < 1920; i += 256){ float x = rew[i] - mean; v = fmaf(x, x, v); }
  red[tid] = v; __syncthreads();
  for (int st = 128; st > 0; st >>= 1){ if (tid < st) red[tid] += red[tid + st]; __syncthreads(); }
  float denom = sqrtf(red[0] / 1919.0f) + 1e-20f;
  if (tid < 128){
    out_sl[tid] = sl[tid] / 15.0f;
    out_ent[tid] = ent[tid] / 15.0f;
    float r = 0.f;
    for (int k = 0; k < 15; k++){
      float rn = (rew[tid * 15 + k] - mean) / denom;
      r = fmaf(lp[tid * 15 + k], rn, r);
    }
    out_reinf[tid] = r;
  }
}

// ---------------- host ----------------
extern "C" void kernel_launch(void* const* d_in, const int* in_sizes, int n_in,
                              void* d_out, int out_size, void* d_ws, size_t ws_size,
                              hipStream_t stream)
{
  const float* x        = (const float*)d_in[0];
  const float* lift_w   = (const float*)d_in[1];
  const float* lift_b   = (const float*)d_in[2];
  const float* unlift_w = (const float*)d_in[3];
  const float* unlift_b = (const float*)d_in[4];
  const float* enc_w1   = (const float*)d_in[5];
  const float* enc_b1   = (const float*)d_in[6];
  const float* enc_w2   = (const float*)d_in[7];
  const float* enc_b2   = (const float*)d_in[8];
  const float* enc_w3   = (const float*)d_in[9];
  const float* enc_b3   = (const float*)d_in[10];
  const float* dec_w1   = (const float*)d_in[11];
  const float* dec_b1   = (const float*)d_in[12];
  const float* dec_w2   = (const float*)d_in[13];
  const float* dec_b2   = (const float*)d_in[14];
  const float* dec_w3   = (const float*)d_in[15];
  const float* dec_b3   = (const float*)d_in[16];
  const float* clf_w1   = (const float*)d_in[17];
  const float* clf_b1   = (const float*)d_in[18];
  const float* clf_w2   = (const float*)d_in[19];
  const float* clf_b2   = (const float*)d_in[20];
  const float* clf_w3   = (const float*)d_in[21];
  const float* clf_b3   = (const float*)d_in[22];
  const float* pol_w1   = (const float*)d_in[23];
  const float* pol_b1   = (const float*)d_in[24];
  const float* pol_w2   = (const float*)d_in[25];
  const float* pol_b2   = (const float*)d_in[26];
  const float* pol_w3   = (const float*)d_in[27];
  const float* pol_b3   = (const float*)d_in[28];

  float* out = (float*)d_out;
  const long U_OFF     = 2097152;
  const long D_OFF     = 4128768;
  const long SL_OFF    = 6160384;
  const long ENT_OFF   = 6160512;
  const long CLF_OFF   = 6160640;
  const long LBL_OFF   = 6168576;
  const long REINF_OFF = 6172544;
  float* recon = out;
  float* u     = out + U_OFF;
  float* dmat  = out + D_OFF;

  char* wsb = (char*)d_ws;
  size_t wo = 0;
  auto alloc = [&](size_t bytes) -> void* {
    void* p = (void*)(wsb + wo);
    wo = (wo + bytes + 255) & ~(size_t)255;
    return p;
  };
  float* logits    = (float*)alloc(115200 * 4);
  float* Y         = (float*)alloc((size_t)3968 * 1024 * 4); // dead after fwd loop -> overlays below
  float* h2ov      = Y;                  // tail clf hidden2 (<= 2048x512 floats)
  float* pbuf      = Y + 2031616;        // dec output 1920x1024 (fits in Y)
  float* W1cat     = (float*)alloc((size_t)524288 * 4);
  float* zb        = (float*)alloc(1024 * 4);
  float* h1        = (float*)alloc((size_t)2048 * 512 * 4);
  float* z_all     = (float*)alloc((size_t)15 * 65536 * 4);
  float* sl        = (float*)alloc(128 * 4);
  float* ent       = (float*)alloc(128 * 4);
  float* lp        = (float*)alloc(1920 * 4);
  float* rew       = (float*)alloc(1920 * 4);
  int*   active    = (int*)alloc(2048 * 4);
  int*   actions   = (int*)alloc(3840 * 4);
  long*  tab_init  = (long*)alloc((size_t)30720 * 2 * 8);
  int*   scat_init = (int*)alloc(30720 * 4);
  long*  tab_loop  = (long*)alloc((size_t)3584 * 2 * 8);
  int*   scat_loop = (int*)alloc(3584 * 4);
  long*  tab_tok16 = (long*)alloc(2048 * 8);
  long*  tab_mgd   = (long*)alloc(1920 * 8);
  (void)ws_size; (void)in_sizes; (void)n_in; (void)out_size;

  uint32_t k7a, k7b, ck0[15], ck1[15], mk0[15], mk1[15];
  { uint32_t a = 0, b = 7; tf2x32(0u, 42u, a, b); k7a = a; k7b = b; }
  for (int it = 0; it < 15; it++){
    { uint32_t a = 0, b = (uint32_t)(100 + it); tf2x32(0u, 42u, a, b); ck0[it] = a; ck1[it] = b; }
    { uint32_t a = 0, b = (uint32_t)(1000 + it); tf2x32(0u, 42u, a, b); mk0[it] = a; mk1[it] = b; }
  }

  auto gemm = [&](int act, const float* A, int lda, const long* atab, int anblk,
                  const float* W, const float* bs, float* C, int rows, int K, int Nn,
                  long cb, int crd, long cos, long cis){
    dim3 g(Nn / 64, rows / 64);
    if (act) gemm_k<1><<<g, 256, 0, stream>>>(A, lda, atab, anblk, W, bs, C, K, Nn, cb, crd, cos, cis);
    else     gemm_k<0><<<g, 256, 0, stream>>>(A, lda, atab, anblk, W, bs, C, K, Nn, cb, crd, cos, cis);
  };

  // ---- init ----
  init_k<<<7936, 256, 0, stream>>>(dmat, out + LBL_OFF, logits, sl, ent, active, zb,
                                   W1cat, pol_w1, pol_b3, tab_init, scat_init, tab_tok16,
                                   tab_mgd);

  // ---- lift + noise ----
  gemm(0, x, 1024, nullptr, 0, lift_w, lift_b, u, 2048, 1024, 512, 0, 16, 15872, 512);
  noise_u_k<<<4096, 256, 0, stream>>>(u, k7a, k7b);

  // ---- Y init for tokens 0..15 ----
  gemm(0, u, 0, tab_tok16, 1, W1cat, zb, Y, 2048, 512, 1024, 0, 16, 31744, 1024);

  // ---- initial policy logits ----
  { dim3 g(4, 240);
    gemm128f_k<<<g, 256, 0, stream>>>(Y, tab_init, pol_b1, pol_w2, pol_b2, pol_w3,
                                      scat_init, logits); }

  // ---- forward merge loop: 2 kernels per iteration ----
  for (int it = 0; it < 15; it++){
    int A = 16 - it;
    if (it > 0){
      int rows = 256 * (15 - it);
      dim3 g(8, rows / 64);
      gemm64f_k<<<g, 256, 0, stream>>>(Y, tab_loop, pol_b1, pol_w2, pol_b2, pol_w3,
                                       scat_loop, logits);
    }
    float log_opt = (float)log((double)(A * (A - 1)));
    sampenc_k<<<128, 1024, 0, stream>>>(logits, active, actions, lp, ent,
                                        u, Y, z_all,
                                        enc_w1, enc_b1, enc_w2, enc_b2, enc_w3, enc_b3,
                                        W1cat, tab_loop, scat_loop, pol_b3,
                                        it, A, ck0[it], ck1[it], mk0[it], mk1[it], log_opt);
  }

  // ---- deferred batched dec over all 15 steps (1920 rows), then osl ----
  gemm(1, z_all, 512, nullptr, 0, dec_w1, dec_b1, h1, 1920, 512, 512, 0, 1, 512, 0);
  gemm(1, h1, 512, nullptr, 0, dec_w2, dec_b2, h2ov, 1920, 512, 512, 0, 1, 512, 0);
  gemm(0, h2ov, 512, nullptr, 0, dec_w3, dec_b3, pbuf, 1920, 512, 1024, 0, 1, 1024, 0);
  oslb_k<<<1920, 256, 0, stream>>>(pbuf, u, actions, sl, rew);

  // ---- reverse unmerge loop: 1 kernel per step ----
  for (int it = 0; it < 15; it++){
    rev_k<<<128, 1024, 0, stream>>>(dmat, u, actions,
                                    dec_w1, dec_b1, dec_w2, dec_b2, dec_w3, dec_b3, it);
  }

  // ---- batched clf over the 15 mgd rows ----
  gemm(1, dmat, 0, tab_mgd, 1, clf_w1, clf_b1, h1, 1920, 512, 512, 0, 1, 512, 0);
  gemm(1, h1, 512, nullptr, 0, clf_w2, clf_b2, h2ov, 1920, 512, 512, 0, 1, 512, 0);
  rowdot_k<<<480, 256, 0, stream>>>(h2ov, 512, clf_w3, clf_b3, 512,
                                    out, CLF_OFF, 128, 2, 62);

  // ---- final clf over d[:, :16], reversed into clf_pred[:, 15:31] ----
  gemm(1, dmat, 0, tab_tok16, 1, clf_w1, clf_b1, h1, 2048, 512, 512, 0, 1, 512, 0);
  gemm(1, h1, 512, nullptr, 0, clf_w2, clf_b2, h2ov, 2048, 512, 512, 0, 1, 512, 0);
  rowdot_k<<<512, 256, 0, stream>>>(h2ov, 512, clf_w3, clf_b3, 512,
                                    out, CLF_OFF + 60, 16, 62, -2);

  // ---- recon = d[:, :16] @ unlift_w + unlift_b ----
  gemm(0, dmat, 0, tab_tok16, 1, unlift_w, unlift_b, recon, 2048, 512, 1024,
       0, 16, 16384, 1024);

  // ---- reward normalization, reinf, per-batch losses ----
  finalize_k<<<1, 256, 0, stream>>>(rew, lp, sl, ent,
                                    out + SL_OFF, out + ENT_OFF, out + REINF_OFF);
}

// Round 6
// 2766.488 us; speedup vs baseline: 1.0288x; 1.0288x over previous
//
#include <hip/hip_runtime.h>
#include <cstdint>
#include <cmath>

#define MASKV -9.0e20f

// ---------------- Threefry-2x32 (JAX-compatible) ----------------
__host__ __device__ inline void tf2x32(uint32_t k0, uint32_t k1, uint32_t& x0, uint32_t& x1){
  uint32_t ks2 = k0 ^ k1 ^ 0x1BD11BDAu;
  x0 += k0; x1 += k1;
#define TFR(r) { x0 += x1; x1 = (x1<<(r))|(x1>>(32-(r))); x1 ^= x0; }
  TFR(13) TFR(15) TFR(26) TFR(6)
  x0 += k1;  x1 += ks2 + 1u;
  TFR(17) TFR(29) TFR(16) TFR(24)
  x0 += ks2; x1 += k0 + 2u;
  TFR(13) TFR(15) TFR(26) TFR(6)
  x0 += k0;  x1 += k1 + 3u;
  TFR(17) TFR(29) TFR(16) TFR(24)
  x0 += k1;  x1 += ks2 + 4u;
  TFR(13) TFR(15) TFR(26) TFR(6)
  x0 += ks2; x1 += k0 + 5u;
#undef TFR
}

__device__ inline uint32_t rbits32(uint32_t k0, uint32_t k1, uint32_t idx){
  uint32_t x0 = 0u, x1 = idx;
  tf2x32(k0, k1, x0, x1);
  return x0 ^ x1;
}

__device__ inline float u01_from_bits(uint32_t bits){
  union { uint32_t u; float f; } c;
  c.u = (bits >> 9) | 0x3f800000u;
  return c.f - 1.0f;
}

__device__ inline float erfinv_f(float x){
  float w = -log1pf(-x*x);
  float p;
  if (w < 5.0f){
    w -= 2.5f;
    p = 2.81022636e-08f;
    p = fmaf(p, w, 3.43273939e-07f);
    p = fmaf(p, w, -3.5233877e-06f);
    p = fmaf(p, w, -4.39150654e-06f);
    p = fmaf(p, w, 0.00021858087f);
    p = fmaf(p, w, -0.00125372503f);
    p = fmaf(p, w, -0.00417768164f);
    p = fmaf(p, w, 0.246640727f);
    p = fmaf(p, w, 1.50140941f);
  } else {
    w = sqrtf(w) - 3.0f;
    p = -0.000200214257f;
    p = fmaf(p, w, 0.000100950558f);
    p = fmaf(p, w, 0.00134934322f);
    p = fmaf(p, w, -0.00367342844f);
    p = fmaf(p, w, 0.00573950773f);
    p = fmaf(p, w, -0.0076224613f);
    p = fmaf(p, w, 0.00943887047f);
    p = fmaf(p, w, 1.00167406f);
    p = fmaf(p, w, 2.83297682f);
  }
  return p * x;
}

__device__ inline float jax_normal(uint32_t k0, uint32_t k1, uint32_t idx){
  float f = u01_from_bits(rbits32(k0, k1, idx));
  float v = fmaf(f, 2.0f, -0.99999994f);
  v = fmaxf(v, -0.99999994f);
  return 1.41421356f * erfinv_f(v);
}

__device__ inline float jax_gumbel(uint32_t k0, uint32_t k1, uint32_t idx){
  float f = u01_from_bits(rbits32(k0, k1, idx));
  f = f + 1.17549435e-38f;
  f = fmaxf(f, 1.17549435e-38f);
  return -logf(-logf(f));
}

// ---------------- small tiled SGEMM (64x64 tile, 4x4 microtile) ----------------
template<int ACT>
__global__ __launch_bounds__(256) void gemm_k(
    const float* __restrict__ A, int lda,
    const long* __restrict__ atab, int anblk,
    const float* __restrict__ W, const float* __restrict__ bias,
    float* __restrict__ C, int K, int N,
    long c_base, int c_rdiv, long c_ostride, long c_istride)
{
  __shared__ float As[16][64];
  __shared__ float Ws[16][64];
  int tid = threadIdx.x;
  int c0 = blockIdx.x * 64;
  int r0 = blockIdx.y * 64;
  int lr = tid >> 2;
  int lk = (tid & 3) << 2;
  int wk = tid >> 4;
  int wc = (tid & 15) << 2;
  int tx = tid & 15;
  int ty = tid >> 4;
  long aoff0 = 0, aoff1 = 0;
  if (atab){
    const long* t = atab + (long)(r0 + lr) * anblk;
    aoff0 = t[0];
    if (anblk == 2) aoff1 = t[1];
  } else {
    aoff0 = (long)(r0 + lr) * lda;
  }
  float acc[4][4];
#pragma unroll
  for (int i = 0; i < 4; i++)
#pragma unroll
    for (int j = 0; j < 4; j++) acc[i][j] = 0.f;

  for (int k0 = 0; k0 < K; k0 += 16){
    int ka = k0 + lk;
    long ab = (atab && anblk == 2 && ka >= 512) ? (aoff1 + (ka - 512)) : (aoff0 + ka);
    float4 av = *(const float4*)(A + ab);
    As[lk + 0][lr] = av.x;
    As[lk + 1][lr] = av.y;
    As[lk + 2][lr] = av.z;
    As[lk + 3][lr] = av.w;
    float4 wv = *(const float4*)(W + (long)(k0 + wk) * N + (c0 + wc));
    *(float4*)&Ws[wk][wc] = wv;
    __syncthreads();
#pragma unroll
    for (int kk = 0; kk < 16; kk++){
      float4 a4 = *(const float4*)&As[kk][ty << 2];
      float4 w4 = *(const float4*)&Ws[kk][tx << 2];
      float aa[4] = {a4.x, a4.y, a4.z, a4.w};
      float ww[4] = {w4.x, w4.y, w4.z, w4.w};
#pragma unroll
      for (int i = 0; i < 4; i++)
#pragma unroll
        for (int j = 0; j < 4; j++)
          acc[i][j] = fmaf(aa[i], ww[j], acc[i][j]);
    }
    __syncthreads();
  }
  float4 bv = *(const float4*)(bias + c0 + (tx << 2));
  float bb[4] = {bv.x, bv.y, bv.z, bv.w};
#pragma unroll
  for (int i = 0; i < 4; i++){
    int r = r0 + (ty << 2) + i;
    long off = c_base + (long)(r / c_rdiv) * c_ostride + (long)(r % c_rdiv) * c_istride
               + c0 + (tx << 2);
    float4 v;
    float o0 = acc[i][0] + bb[0], o1 = acc[i][1] + bb[1];
    float o2 = acc[i][2] + bb[2], o3 = acc[i][3] + bb[3];
    if (ACT){ o0 = fmaxf(o0, 0.f); o1 = fmaxf(o1, 0.f); o2 = fmaxf(o2, 0.f); o3 = fmaxf(o3, 0.f); }
    v.x = o0; v.y = o1; v.z = o2; v.w = o3;
    *(float4*)(C + off) = v;
  }
}

// ---------------- 128-tile fused policy GEMM (initial step, 30720 rows) ----------------
// microtile = 2x(4 rows) x 2x(4 cols), halves 64 apart -> conflict-free LDS reads
__global__ __launch_bounds__(256) void gemm128f_k(
    const float* __restrict__ Y,
    const long* __restrict__ atab,
    const float* __restrict__ b1,
    const float* __restrict__ W2, const float* __restrict__ b2,
    const float* __restrict__ w3,
    const int* __restrict__ scat, float* __restrict__ logits)
{
  __shared__ float As[16][132];
  __shared__ float Ws[16][132];
  int tid = threadIdx.x;
  int c0 = blockIdx.x * 128;
  int r0 = blockIdx.y * 128;
  int tx = tid & 15, ty = tid >> 4;
  int rA0 = tid >> 2;
  int rA1 = rA0 + 64;
  int kq = (tid & 3) << 2;
  long a00 = atab[(long)(r0 + rA0) * 2];
  long a01 = atab[(long)(r0 + rA0) * 2 + 1];
  long a10 = atab[(long)(r0 + rA1) * 2];
  long a11 = atab[(long)(r0 + rA1) * 2 + 1];
  int wk0 = tid >> 5, wc0 = (tid & 31) << 2;
  float acc[8][8];
#pragma unroll
  for (int i = 0; i < 8; i++)
#pragma unroll
    for (int j = 0; j < 8; j++) acc[i][j] = 0.f;

  for (int k0 = 0; k0 < 512; k0 += 16){
    int ka = k0 + kq;
    float4 p0 = *(const float4*)(Y + a00 + ka);
    float4 q0 = *(const float4*)(Y + a01 + ka);
    float4 p1 = *(const float4*)(Y + a10 + ka);
    float4 q1 = *(const float4*)(Y + a11 + ka);
    float4 bb = *(const float4*)(b1 + ka);
    As[kq + 0][rA0] = fmaxf(p0.x + q0.x + bb.x, 0.f);
    As[kq + 1][rA0] = fmaxf(p0.y + q0.y + bb.y, 0.f);
    As[kq + 2][rA0] = fmaxf(p0.z + q0.z + bb.z, 0.f);
    As[kq + 3][rA0] = fmaxf(p0.w + q0.w + bb.w, 0.f);
    As[kq + 0][rA1] = fmaxf(p1.x + q1.x + bb.x, 0.f);
    As[kq + 1][rA1] = fmaxf(p1.y + q1.y + bb.y, 0.f);
    As[kq + 2][rA1] = fmaxf(p1.z + q1.z + bb.z, 0.f);
    As[kq + 3][rA1] = fmaxf(p1.w + q1.w + bb.w, 0.f);
    *(float4*)&Ws[wk0][wc0]     = *(const float4*)(W2 + (long)(k0 + wk0) * 512 + (c0 + wc0));
    *(float4*)&Ws[wk0 + 8][wc0] = *(const float4*)(W2 + (long)(k0 + wk0 + 8) * 512 + (c0 + wc0));
    __syncthreads();
#pragma unroll
    for (int kk = 0; kk < 16; kk++){
      float a0[8], w0[8];
      *(float4*)&a0[0] = *(const float4*)&As[kk][ty << 2];
      *(float4*)&a0[4] = *(const float4*)&As[kk][(ty << 2) + 64];
      *(float4*)&w0[0] = *(const float4*)&Ws[kk][tx << 2];
      *(float4*)&w0[4] = *(const float4*)&Ws[kk][(tx << 2) + 64];
#pragma unroll
      for (int i = 0; i < 8; i++)
#pragma unroll
        for (int j = 0; j < 8; j++)
          acc[i][j] = fmaf(a0[i], w0[j], acc[i][j]);
    }
    __syncthreads();
  }
  float bb[8], w3v[8];
  *(float4*)&bb[0]  = *(const float4*)(b2 + c0 + (tx << 2));
  *(float4*)&bb[4]  = *(const float4*)(b2 + c0 + (tx << 2) + 64);
  *(float4*)&w3v[0] = *(const float4*)(w3 + c0 + (tx << 2));
  *(float4*)&w3v[4] = *(const float4*)(w3 + c0 + (tx << 2) + 64);
#pragma unroll
  for (int i = 0; i < 8; i++){
    float p = 0.f;
#pragma unroll
    for (int j = 0; j < 8; j++)
      p = fmaf(fmaxf(acc[i][j] + bb[j], 0.f), w3v[j], p);
    for (int m = 1; m < 16; m <<= 1) p += __shfl_xor(p, m);
    if (tx == 0){
      int rr = (i < 4) ? ((ty << 2) + i) : (64 + (ty << 2) + (i - 4));
      atomicAdd(logits + scat[r0 + rr], p);
    }
  }
}

// ---------------- 64-tile fused policy GEMM (in-loop, rows <= 3584) ----------------
__global__ __launch_bounds__(256) void gemm64f_k(
    const float* __restrict__ Y,
    const long* __restrict__ atab,
    const float* __restrict__ b1,
    const float* __restrict__ W2, const float* __restrict__ b2,
    const float* __restrict__ w3,
    const int* __restrict__ scat, float* __restrict__ logits)
{
  __shared__ float As[16][64];
  __shared__ float Ws[16][64];
  int tid = threadIdx.x;
  int c0 = blockIdx.x * 64;
  int r0 = blockIdx.y * 64;
  int lr = tid >> 2;
  int lk = (tid & 3) << 2;
  int wk = tid >> 4;
  int wc = (tid & 15) << 2;
  int tx = tid & 15;
  int ty = tid >> 4;
  long a0 = atab[(long)(r0 + lr) * 2];
  long a1 = atab[(long)(r0 + lr) * 2 + 1];
  float acc[4][4];
#pragma unroll
  for (int i = 0; i < 4; i++)
#pragma unroll
    for (int j = 0; j < 4; j++) acc[i][j] = 0.f;

  for (int k0 = 0; k0 < 512; k0 += 16){
    int ka = k0 + lk;
    float4 p = *(const float4*)(Y + a0 + ka);
    float4 q = *(const float4*)(Y + a1 + ka);
    float4 bb = *(const float4*)(b1 + ka);
    As[lk + 0][lr] = fmaxf(p.x + q.x + bb.x, 0.f);
    As[lk + 1][lr] = fmaxf(p.y + q.y + bb.y, 0.f);
    As[lk + 2][lr] = fmaxf(p.z + q.z + bb.z, 0.f);
    As[lk + 3][lr] = fmaxf(p.w + q.w + bb.w, 0.f);
    *(float4*)&Ws[wk][wc] = *(const float4*)(W2 + (long)(k0 + wk) * 512 + (c0 + wc));
    __syncthreads();
#pragma unroll
    for (int kk = 0; kk < 16; kk++){
      float4 a4 = *(const float4*)&As[kk][ty << 2];
      float4 w4 = *(const float4*)&Ws[kk][tx << 2];
      float aa[4] = {a4.x, a4.y, a4.z, a4.w};
      float ww[4] = {w4.x, w4.y, w4.z, w4.w};
#pragma unroll
      for (int i = 0; i < 4; i++)
#pragma unroll
        for (int j = 0; j < 4; j++)
          acc[i][j] = fmaf(aa[i], ww[j], acc[i][j]);
    }
    __syncthreads();
  }
  float bb4[4], w34[4];
  *(float4*)&bb4[0] = *(const float4*)(b2 + c0 + (tx << 2));
  *(float4*)&w34[0] = *(const float4*)(w3 + c0 + (tx << 2));
#pragma unroll
  for (int i = 0; i < 4; i++){
    float p = 0.f;
#pragma unroll
    for (int j = 0; j < 4; j++)
      p = fmaf(fmaxf(acc[i][j] + bb4[j], 0.f), w34[j], p);
    for (int m = 1; m < 16; m <<= 1) p += __shfl_xor(p, m);
    if (tx == 0){
      int r = r0 + (ty << 2) + i;
      atomicAdd(logits + scat[r], p);
    }
  }
}

// N=2 final layer with scatter table: one wave per row
__global__ __launch_bounds__(256) void rowdot2_k(
    const float* __restrict__ A, int lda,
    const float* __restrict__ W, const float* __restrict__ bias,
    int K, float* __restrict__ out, const int* __restrict__ scat)
{
  int wid = threadIdx.x >> 6, lane = threadIdx.x & 63;
  int r = blockIdx.x * 4 + wid;
  const float* a = A + (long)r * lda;
  float s0 = 0.f, s1 = 0.f;
  for (int k = lane; k < K; k += 64){
    float x = a[k];
    s0 = fmaf(x, W[k * 2], s0);
    s1 = fmaf(x, W[k * 2 + 1], s1);
  }
  for (int off = 32; off > 0; off >>= 1){
    s0 += __shfl_down(s0, off);
    s1 += __shfl_down(s1, off);
  }
  if (lane == 0){
    long o = scat[r];
    out[o] = s0 + bias[0];
    out[o + 1] = s1 + bias[1];
  }
}

// ---------------- wide per-layer matvec kernels (row/block, col/thread) ----------------
// enc layer1: src = pair gather (K=1024), C=512, relu. grid (2, 128)
__global__ __launch_bounds__(256) void pairmv_k(
    const float* __restrict__ u, const long* __restrict__ tab_pair,
    const float* __restrict__ W, const float* __restrict__ bias,
    float* __restrict__ dst)
{
  __shared__ float s[1024];
  int b = blockIdx.y, tid = threadIdx.x;
  int c = blockIdx.x * 256 + tid;
  long t0 = tab_pair[b * 2], t1 = tab_pair[b * 2 + 1];
  s[tid]       = u[t0 + tid];
  s[tid + 256] = u[t0 + tid + 256];
  s[tid + 512] = u[t1 + tid];
  s[tid + 768] = u[t1 + tid + 256];
  __syncthreads();
  float a0 = 0.f, a1 = 0.f, a2 = 0.f, a3 = 0.f;
#pragma unroll 8
  for (int k = 0; k < 1024; k += 4){
    a0 = fmaf(s[k],     W[(long)k * 512 + c],       a0);
    a1 = fmaf(s[k + 1], W[(long)(k + 1) * 512 + c], a1);
    a2 = fmaf(s[k + 2], W[(long)(k + 2) * 512 + c], a2);
    a3 = fmaf(s[k + 3], W[(long)(k + 3) * 512 + c], a3);
  }
  float v = ((a0 + a1) + (a2 + a3)) + bias[c];
  dst[(long)b * 512 + c] = fmaxf(v, 0.f);
}

// generic K=512 -> C=512 relu layer. grid (2, 128)
__global__ __launch_bounds__(256) void mvrelu_k(
    const float* __restrict__ src, long sstride,
    const float* __restrict__ W, const float* __restrict__ bias,
    float* __restrict__ dst)
{
  __shared__ float s[512];
  int b = blockIdx.y, tid = threadIdx.x;
  int c = blockIdx.x * 256 + tid;
  const float* sr = src + (long)b * sstride;
  s[tid] = sr[tid];
  s[tid + 256] = sr[tid + 256];
  __syncthreads();
  float a0 = 0.f, a1 = 0.f, a2 = 0.f, a3 = 0.f;
#pragma unroll 8
  for (int k = 0; k < 512; k += 4){
    a0 = fmaf(s[k],     W[(long)k * 512 + c],       a0);
    a1 = fmaf(s[k + 1], W[(long)(k + 1) * 512 + c], a1);
    a2 = fmaf(s[k + 2], W[(long)(k + 2) * 512 + c], a2);
    a3 = fmaf(s[k + 3], W[(long)(k + 3) * 512 + c], a3);
  }
  float v = ((a0 + a1) + (a2 + a3)) + bias[c];
  dst[(long)b * 512 + c] = fmaxf(v, 0.f);
}

// enc layer3 + noise/u-append + Y-row: one block (512 thr) per batch row
__global__ __launch_bounds__(512) void lay3y_k(
    const float* __restrict__ src,
    const float* __restrict__ W, const float* __restrict__ bias,
    const float* __restrict__ W1cat,
    float* __restrict__ z_all, float* __restrict__ u, float* __restrict__ Y,
    int it, uint32_t k0, uint32_t k1)
{
  __shared__ float s[512];
  __shared__ float zu[512];
  int b = blockIdx.x, tid = threadIdx.x;
  s[tid] = src[(long)b * 512 + tid];
  __syncthreads();
  float a0 = 0.f, a1 = 0.f, a2 = 0.f, a3 = 0.f;
#pragma unroll 8
  for (int k = 0; k < 512; k += 4){
    a0 = fmaf(s[k],     W[(long)k * 512 + tid],       a0);
    a1 = fmaf(s[k + 1], W[(long)(k + 1) * 512 + tid], a1);
    a2 = fmaf(s[k + 2], W[(long)(k + 2) * 512 + tid], a2);
    a3 = fmaf(s[k + 3], W[(long)(k + 3) * 512 + tid], a3);
  }
  float z = ((a0 + a1) + (a2 + a3)) + bias[tid];
  z_all[(long)it * 65536 + (long)b * 512 + tid] = z;
  float uv = z + 0.01f * jax_normal(k0, k1, (uint32_t)(b * 512 + tid));
  u[((long)(b * 31 + 16 + it)) * 512 + tid] = uv;
  zu[tid] = uv;
  __syncthreads();
  if (it < 14){
    float c0a = 0.f, c0b = 0.f, c1a = 0.f, c1b = 0.f;
#pragma unroll 4
    for (int k = 0; k < 512; k += 2){
      float v0 = zu[k], v1 = zu[k + 1];
      c0a = fmaf(v0, W1cat[(long)k * 1024 + tid],             c0a);
      c1a = fmaf(v0, W1cat[(long)k * 1024 + tid + 512],       c1a);
      c0b = fmaf(v1, W1cat[(long)(k + 1) * 1024 + tid],       c0b);
      c1b = fmaf(v1, W1cat[(long)(k + 1) * 1024 + tid + 512], c1b);
    }
    long yo = ((long)(b * 31 + 16 + it)) * 1024;
    Y[yo + tid] = c0a + c0b;
    Y[yo + tid + 512] = c1a + c1b;
  }
}

// reverse layer3 + scatter into dmat. grid (4, 128)
__global__ __launch_bounds__(256) void rev3_k(
    const float* __restrict__ src,
    const float* __restrict__ W, const float* __restrict__ bias,
    float* __restrict__ dmat, const int* __restrict__ actions, int it)
{
  __shared__ float s[512];
  int b = blockIdx.y, tid = threadIdx.x;
  int p = blockIdx.x * 256 + tid;
  const float* sr = src + (long)b * 512;
  s[tid] = sr[tid];
  s[tid + 256] = sr[tid + 256];
  __syncthreads();
  float a0 = 0.f, a1 = 0.f, a2 = 0.f, a3 = 0.f;
#pragma unroll 8
  for (int k = 0; k < 512; k += 4){
    a0 = fmaf(s[k],     W[(long)k * 1024 + p],       a0);
    a1 = fmaf(s[k + 1], W[(long)(k + 1) * 1024 + p], a1);
    a2 = fmaf(s[k + 2], W[(long)(k + 2) * 1024 + p], a2);
    a3 = fmaf(s[k + 3], W[(long)(k + 3) * 1024 + p], a3);
  }
  float v = ((a0 + a1) + (a2 + a3)) + bias[p];
  int fit = 14 - it;
  int s0 = actions[(b * 15 + fit) * 2];
  int s1 = actions[(b * 15 + fit) * 2 + 1];
  int node = (p < 512) ? s0 : s1;
  int ee = p & 511;
  dmat[((long)(b * 31 + node)) * 512 + ee] = v;
}

// batched osl over all steps: grid 1920 (r = it*128 + b)
__global__ __launch_bounds__(256) void oslb_k(
    const float* __restrict__ pred, const float* __restrict__ u,
    const int* __restrict__ actions, float* __restrict__ sl, float* __restrict__ rew)
{
  int r = blockIdx.x, tid = threadIdx.x;
  int it = r >> 7, b = r & 127;
  int s0 = actions[(b * 15 + it) * 2];
  int s1 = actions[(b * 15 + it) * 2 + 1];
  const float* t0 = u + ((long)(b * 31 + s0)) * 512;
  const float* t1 = u + ((long)(b * 31 + s1)) * 512;
  const float* p = pred + (long)r * 1024;
  float s = 0.f;
  for (int k = tid; k < 512; k += 256){
    float d0 = p[k] - t0[k];       s = fmaf(d0, d0, s);
    float d1 = p[k + 512] - t1[k]; s = fmaf(d1, d1, s);
  }
  __shared__ float red[256];
  red[tid] = s; __syncthreads();
  for (int st = 128; st > 0; st >>= 1){ if (tid < st) red[tid] += red[tid + st]; __syncthreads(); }
  if (tid == 0){
    float osl = red[0] / 1024.0f;
    atomicAdd(sl + b, osl);
    rew[b * 15 + it] = -osl;
  }
}

// ---------------- init (no dmat zeroing: every cell of d is provably overwritten) ----------------
__global__ __launch_bounds__(256) void init_k(float* __restrict__ lbl,
    float* __restrict__ logits, float* __restrict__ sl, float* __restrict__ ent,
    int* __restrict__ active, float* __restrict__ zb,
    float* __restrict__ W1cat, const float* __restrict__ pol_w1, const float* __restrict__ pol_b3,
    long* __restrict__ tab_init, int* __restrict__ scat_init, long* __restrict__ tab_tok16,
    long* __restrict__ tab_mgd, int* __restrict__ scat_clf, long clf_off)
{
  long i = (long)blockIdx.x * 256 + threadIdx.x;
  if (i < 524288L){
    int k = (int)(i >> 10), n = (int)(i & 1023);
    W1cat[i] = (n < 512) ? pol_w1[(long)k * 512 + n] : pol_w1[(long)(k + 512) * 512 + (n - 512)];
  }
  if (i < 115200L){
    int rem = (int)(i % 900);
    int rr = rem / 30, cc = rem % 30;
    logits[i] = (rr < 16 && cc < 16 && rr != cc) ? pol_b3[0] : MASKV;
  }
  if (i < 30720L){
    int r = (int)i;
    int pk = r >> 7, b = r & 127;
    int ii2 = pk / 15, jr = pk % 15;
    int jj2 = jr + (jr >= ii2 ? 1 : 0);
    tab_init[r * 2]     = ((long)(b * 31 + ii2)) * 1024;
    tab_init[r * 2 + 1] = ((long)(b * 31 + jj2)) * 1024 + 512;
    scat_init[r] = b * 900 + ii2 * 30 + jj2;
  }
  if (i < 3968L){
    lbl[i] = ((i % 31) < 15) ? 1.0f : 0.0f;
    // combined clf output scatter: rows 0..1919 = mgd (b=r&127, it=r>>7),
    // rows 1920..3967 = tok16 reversed (b=rr>>4, n=rr&15 -> col 30-n)
    int r = (int)i;
    if (r < 1920){
      scat_clf[r] = (int)(clf_off + (long)(r & 127) * 62 + (r >> 7) * 2);
    } else {
      int rr = r - 1920;
      scat_clf[r] = (int)(clf_off + (long)(rr >> 4) * 62 + 60 - ((rr & 15) << 1));
    }
  }
  if (i < 2048L){
    active[i] = (int)(i & 15);
    tab_tok16[i] = ((long)((i >> 4) * 31 + (i & 15))) * 512;
  }
  if (i < 1920L){
    int it = (int)(i >> 7), b = (int)(i & 127);
    tab_mgd[i] = ((long)(b * 31 + 30 - it)) * 512;
  }
  if (i < 1024L)  zb[i] = 0.f;
  if (i < 128L){ sl[i] = 0.f; ent[i] = 0.f; }
}

__global__ __launch_bounds__(256) void noise_u_k(float* __restrict__ u, uint32_t k0, uint32_t k1){
  uint32_t e = blockIdx.x * 256u + threadIdx.x; // < 1048576
  uint32_t b = e >> 13, rem = e & 8191u, n = rem >> 9, ee = rem & 511u;
  float nr = jax_normal(k0, k1, e);
  long off = ((long)(b * 31u + n)) * 512 + ee;
  u[off] += 0.01f * nr;
}

__global__ __launch_bounds__(256) void build_d_k(float* __restrict__ dmat, const float* __restrict__ u){
  int e = blockIdx.x * 256 + threadIdx.x; // 65536
  int b = e >> 9, ee = e & 511;
  long off = ((long)(b * 31 + 30)) * 512 + ee;
  dmat[off] = u[off];
}

// softmax stats + entropy + gumbel-argmax + mask + active update + next tables + b3 preset
__global__ __launch_bounds__(256) void sample_k(float* __restrict__ logits, int* __restrict__ active,
    int* __restrict__ actions, float* __restrict__ lp, float* __restrict__ ent,
    int it, int A, uint32_t k0, uint32_t k1, float log_opt,
    long* __restrict__ tab_loop, int* __restrict__ scat_loop, long* __restrict__ tab_pair,
    const float* __restrict__ pol_b3)
{
  int b = blockIdx.x, tid = threadIdx.x;
  float* Lg = logits + (long)b * 900;
  __shared__ float red[256];
  __shared__ int redi[256];
  __shared__ int ss0, ss1;

  float v = -3.4e38f;
  for (int j = tid; j < 900; j += 256) v = fmaxf(v, Lg[j]);
  red[tid] = v; __syncthreads();
  for (int s = 128; s > 0; s >>= 1){ if (tid < s) red[tid] = fmaxf(red[tid], red[tid + s]); __syncthreads(); }
  float m = red[0]; __syncthreads();

  float acc = 0.f;
  for (int j = tid; j < 900; j += 256) acc += expf(Lg[j] - m);
  red[tid] = acc; __syncthreads();
  for (int s = 128; s > 0; s >>= 1){ if (tid < s) red[tid] += red[tid + s]; __syncthreads(); }
  float ssum = red[0]; __syncthreads();

  float es = 0.f;
  for (int j = tid; j < 900; j += 256){
    float l = Lg[j];
    if (l > MASKV){
      float p = expf(l - m) / ssum;
      float pa = p + 1e-20f;
      es += pa * logf(pa);
    }
  }
  red[tid] = es; __syncthreads();
  for (int s = 128; s > 0; s >>= 1){ if (tid < s) red[tid] += red[tid + s]; __syncthreads(); }
  if (tid == 0) ent[b] += -(red[0]) / log_opt;
  __syncthreads();

  float bv = -3.4e38f; int bi = 0;
  for (int j = tid; j < 900; j += 256){
    float g = jax_gumbel(k0, k1, (uint32_t)(b * 900 + j));
    float val = Lg[j] + g;
    if (val > bv){ bv = val; bi = j; }
  }
  red[tid] = bv; redi[tid] = bi; __syncthreads();
  for (int s = 128; s > 0; s >>= 1){
    if (tid < s){
      float o = red[tid + s]; int oi = redi[tid + s];
      if (o > red[tid] || (o == red[tid] && oi < redi[tid])){ red[tid] = o; redi[tid] = oi; }
    }
    __syncthreads();
  }
  if (tid == 0){
    int sf = redi[0];
    int s0 = sf / 30, s1 = sf % 30;
    ss0 = s0; ss1 = s1;
    actions[(b * 15 + it) * 2] = s0;
    actions[(b * 15 + it) * 2 + 1] = s1;
    lp[b * 15 + it] = Lg[sf] - m - logf(ssum);
    tab_pair[b * 2]     = ((long)(b * 31 + s0)) * 512;
    tab_pair[b * 2 + 1] = ((long)(b * 31 + s1)) * 512;
  }
  __syncthreads();
  int s0 = ss0, s1 = ss1;
  if (tid < 30){
    Lg[s0 * 30 + tid] = MASKV;
    Lg[s1 * 30 + tid] = MASKV;
    Lg[tid * 30 + s0] = MASKV;
    Lg[tid * 30 + s1] = MASKV;
  }
  if (tid == 0){
    float b3v = pol_b3[0];
    int buf[16]; int c = 0;
    for (int k = 0; k < A; k++){
      int a = active[b * 16 + k];
      if (a != s0 && a != s1) buf[c++] = a;
    }
    int nt2 = 16 + it;
    buf[c++] = nt2;
    for (int k = 0; k < c; k++) active[b * 16 + k] = buf[k];
    int na2 = c - 1;
    for (int j = 0; j < na2; j++){
      int q = buf[j];
      int r1 = j * 128 + b;
      tab_loop[r1 * 2]     = ((long)(b * 31 + nt2)) * 1024;
      tab_loop[r1 * 2 + 1] = ((long)(b * 31 + q)) * 1024 + 512;
      int sc1 = b * 900 + nt2 * 30 + q;
      scat_loop[r1] = sc1;
      logits[sc1] = b3v;
      int r2 = (na2 + j) * 128 + b;
      tab_loop[r2 * 2]     = ((long)(b * 31 + q)) * 1024;
      tab_loop[r2 * 2 + 1] = ((long)(b * 31 + nt2)) * 1024 + 512;
      int sc2 = b * 900 + q * 30 + nt2;
      scat_loop[r2] = sc2;
      logits[sc2] = b3v;
    }
  }
}

__global__ __launch_bounds__(256) void finalize_k(const float* __restrict__ rew,
    const float* __restrict__ lp, const float* __restrict__ sl, const float* __restrict__ ent,
    float* __restrict__ out_sl, float* __restrict__ out_ent, float* __restrict__ out_reinf)
{
  __shared__ float red[256];
  int tid = threadIdx.x;
  float s = 0.f;
  for (int i = tid; i < 1920; i += 256) s += rew[i];
  red[tid] = s; __syncthreads();
  for (int st = 128; st > 0; st >>= 1){ if (tid < st) red[tid] += red[tid + st]; __syncthreads(); }
  float mean = red[0] / 1920.0f; __syncthreads();
  float v = 0.f;
  for (int i = tid; i < 1920; i += 256){ float x = rew[i] - mean; v = fmaf(x, x, v); }
  red[tid] = v; __syncthreads();
  for (int st = 128; st > 0; st >>= 1){ if (tid < st) red[tid] += red[tid + st]; __syncthreads(); }
  float denom = sqrtf(red[0] / 1919.0f) + 1e-20f;
  if (tid < 128){
    out_sl[tid] = sl[tid] / 15.0f;
    out_ent[tid] = ent[tid] / 15.0f;
    float r = 0.f;
    for (int k = 0; k < 15; k++){
      float rn = (rew[tid * 15 + k] - mean) / denom;
      r = fmaf(lp[tid * 15 + k], rn, r);
    }
    out_reinf[tid] = r;
  }
}

// ---------------- host ----------------
extern "C" void kernel_launch(void* const* d_in, const int* in_sizes, int n_in,
                              void* d_out, int out_size, void* d_ws, size_t ws_size,
                              hipStream_t stream)
{
  const float* x        = (const float*)d_in[0];
  const float* lift_w   = (const float*)d_in[1];
  const float* lift_b   = (const float*)d_in[2];
  const float* unlift_w = (const float*)d_in[3];
  const float* unlift_b = (const float*)d_in[4];
  const float* enc_w1   = (const float*)d_in[5];
  const float* enc_b1   = (const float*)d_in[6];
  const float* enc_w2   = (const float*)d_in[7];
  const float* enc_b2   = (const float*)d_in[8];
  const float* enc_w3   = (const float*)d_in[9];
  const float* enc_b3   = (const float*)d_in[10];
  const float* dec_w1   = (const float*)d_in[11];
  const float* dec_b1   = (const float*)d_in[12];
  const float* dec_w2   = (const float*)d_in[13];
  const float* dec_b2   = (const float*)d_in[14];
  const float* dec_w3   = (const float*)d_in[15];
  const float* dec_b3   = (const float*)d_in[16];
  const float* clf_w1   = (const float*)d_in[17];
  const float* clf_b1   = (const float*)d_in[18];
  const float* clf_w2   = (const float*)d_in[19];
  const float* clf_b2   = (const float*)d_in[20];
  const float* clf_w3   = (const float*)d_in[21];
  const float* clf_b3   = (const float*)d_in[22];
  const float* pol_w1   = (const float*)d_in[23];
  const float* pol_b1   = (const float*)d_in[24];
  const float* pol_w2   = (const float*)d_in[25];
  const float* pol_b2   = (const float*)d_in[26];
  const float* pol_w3   = (const float*)d_in[27];
  const float* pol_b3   = (const float*)d_in[28];

  float* out = (float*)d_out;
  const long U_OFF     = 2097152;
  const long D_OFF     = 4128768;
  const long SL_OFF    = 6160384;
  const long ENT_OFF   = 6160512;
  const long CLF_OFF   = 6160640;
  const long LBL_OFF   = 6168576;
  const long REINF_OFF = 6172544;
  float* recon = out;
  float* u     = out + U_OFF;
  float* dmat  = out + D_OFF;

  char* wsb = (char*)d_ws;
  size_t wo = 0;
  auto alloc = [&](size_t bytes) -> void* {
    void* p = (void*)(wsb + wo);
    wo = (wo + bytes + 255) & ~(size_t)255;
    return p;
  };
  float* logits    = (float*)alloc(115200 * 4);
  float* Y         = (float*)alloc((size_t)3968 * 1024 * 4); // dead after fwd loop -> overlays:
  float* h1clf     = Y;                  // tail clf hidden1 (3968x512)
  float* pbuf      = Y + 2031616;        // dec output 1920x1024 (consumed by oslb), then clf h2 (3968x512)
  float* h2clf     = Y + 2031616;
  float* W1cat     = (float*)alloc((size_t)524288 * 4);
  float* zb        = (float*)alloc(1024 * 4);
  float* h1        = (float*)alloc((size_t)2048 * 512 * 4);
  float* h2        = (float*)alloc((size_t)2048 * 512 * 4);
  float* z_all     = (float*)alloc((size_t)15 * 65536 * 4);
  float* sl        = (float*)alloc(128 * 4);
  float* ent       = (float*)alloc(128 * 4);
  float* lp        = (float*)alloc(1920 * 4);
  float* rew       = (float*)alloc(1920 * 4);
  int*   active    = (int*)alloc(2048 * 4);
  int*   actions   = (int*)alloc(3840 * 4);
  long*  tab_init  = (long*)alloc((size_t)30720 * 2 * 8);
  int*   scat_init = (int*)alloc(30720 * 4);
  long*  tab_loop  = (long*)alloc((size_t)3584 * 2 * 8);
  int*   scat_loop = (int*)alloc(3584 * 4);
  long*  tab_pair  = (long*)alloc(256 * 8);
  long*  tab_mgd   = (long*)alloc(1920 * 8);   // 15360 B, 256-aligned -> contiguous with next
  long*  tab_tok16 = (long*)alloc(2048 * 8);   // tab_clf = tab_mgd (3968 rows total)
  int*   scat_clf  = (int*)alloc(3968 * 4);
  long*  tab_clf   = tab_mgd;
  (void)ws_size; (void)in_sizes; (void)n_in; (void)out_size;

  uint32_t k7a, k7b, ck0[15], ck1[15], mk0[15], mk1[15];
  { uint32_t a = 0, b = 7; tf2x32(0u, 42u, a, b); k7a = a; k7b = b; }
  for (int it = 0; it < 15; it++){
    { uint32_t a = 0, b = (uint32_t)(100 + it); tf2x32(0u, 42u, a, b); ck0[it] = a; ck1[it] = b; }
    { uint32_t a = 0, b = (uint32_t)(1000 + it); tf2x32(0u, 42u, a, b); mk0[it] = a; mk1[it] = b; }
  }

  auto gemm = [&](int act, const float* A, int lda, const long* atab, int anblk,
                  const float* W, const float* bs, float* C, int rows, int K, int Nn,
                  long cb, int crd, long cos, long cis){
    dim3 g(Nn / 64, rows / 64);
    if (act) gemm_k<1><<<g, 256, 0, stream>>>(A, lda, atab, anblk, W, bs, C, K, Nn, cb, crd, cos, cis);
    else     gemm_k<0><<<g, 256, 0, stream>>>(A, lda, atab, anblk, W, bs, C, K, Nn, cb, crd, cos, cis);
  };

  // ---- init ----
  init_k<<<2048, 256, 0, stream>>>(out + LBL_OFF, logits, sl, ent, active, zb,
                                   W1cat, pol_w1, pol_b3, tab_init, scat_init, tab_tok16,
                                   tab_mgd, scat_clf, CLF_OFF);

  // ---- lift + noise ----
  gemm(0, x, 1024, nullptr, 0, lift_w, lift_b, u, 2048, 1024, 512, 0, 16, 15872, 512);
  noise_u_k<<<4096, 256, 0, stream>>>(u, k7a, k7b);

  // ---- Y init for tokens 0..15 ----
  gemm(0, u, 0, tab_tok16, 1, W1cat, zb, Y, 2048, 512, 1024, 0, 16, 31744, 1024);

  // ---- initial policy logits ----
  { dim3 g(4, 240);
    gemm128f_k<<<g, 256, 0, stream>>>(Y, tab_init, pol_b1, pol_w2, pol_b2, pol_w3,
                                      scat_init, logits); }

  // ---- forward merge loop: 5 kernels per iteration (gemm64f only for it>0) ----
  for (int it = 0; it < 15; it++){
    int A = 16 - it;
    if (it > 0){
      int rows = 256 * (15 - it);
      dim3 g(8, rows / 64);
      gemm64f_k<<<g, 256, 0, stream>>>(Y, tab_loop, pol_b1, pol_w2, pol_b2, pol_w3,
                                       scat_loop, logits);
    }
    float log_opt = (float)log((double)(A * (A - 1)));
    sample_k<<<128, 256, 0, stream>>>(logits, active, actions, lp, ent, it, A,
                                      ck0[it], ck1[it], log_opt,
                                      tab_loop, scat_loop, tab_pair, pol_b3);
    { dim3 g(2, 128);
      pairmv_k<<<g, 256, 0, stream>>>(u, tab_pair, enc_w1, enc_b1, h1); }
    { dim3 g(2, 128);
      mvrelu_k<<<g, 256, 0, stream>>>(h1, 512, enc_w2, enc_b2, h2); }
    lay3y_k<<<128, 512, 0, stream>>>(h2, enc_w3, enc_b3, W1cat, z_all, u, Y,
                                     it, mk0[it], mk1[it]);
  }

  // ---- deferred batched dec over all 15 steps (1920 rows), then osl ----
  gemm(1, z_all, 512, nullptr, 0, dec_w1, dec_b1, h1, 1920, 512, 512, 0, 1, 512, 0);
  gemm(1, h1, 512, nullptr, 0, dec_w2, dec_b2, h2, 1920, 512, 512, 0, 1, 512, 0);
  gemm(0, h2, 512, nullptr, 0, dec_w3, dec_b3, pbuf, 1920, 512, 1024, 0, 1, 1024, 0);
  oslb_k<<<1920, 256, 0, stream>>>(pbuf, u, actions, sl, rew);

  // ---- d init (only token 30 active) ----
  build_d_k<<<256, 256, 0, stream>>>(dmat, u);

  // ---- reverse unmerge loop: 3 wide layers per step; layer1 reads dmat directly ----
  for (int it = 0; it < 15; it++){
    int tok = 30 - it;
    { dim3 g(2, 128);
      mvrelu_k<<<g, 256, 0, stream>>>(dmat + (long)tok * 512, 15872, dec_w1, dec_b1, h1); }
    { dim3 g(2, 128);
      mvrelu_k<<<g, 256, 0, stream>>>(h1, 512, dec_w2, dec_b2, h2); }
    { dim3 g(4, 128);
      rev3_k<<<g, 256, 0, stream>>>(h2, dec_w3, dec_b3, dmat, actions, it); }
  }

  // ---- combined clf over mgd rows (1920) + final d[:, :16] rows (2048) = 3968 rows ----
  gemm(1, dmat, 0, tab_clf, 1, clf_w1, clf_b1, h1clf, 3968, 512, 512, 0, 1, 512, 0);
  gemm(1, h1clf, 512, nullptr, 0, clf_w2, clf_b2, h2clf, 3968, 512, 512, 0, 1, 512, 0);
  rowdot2_k<<<992, 256, 0, stream>>>(h2clf, 512, clf_w3, clf_b3, 512, out, scat_clf);

  // ---- recon = d[:, :16] @ unlift_w + unlift_b ----
  gemm(0, dmat, 0, tab_tok16, 1, unlift_w, unlift_b, recon, 2048, 512, 1024,
       0, 16, 16384, 1024);

  // ---- reward normalization, reinf, per-batch losses ----
  finalize_k<<<1, 256, 0, stream>>>(rew, lp, sl, ent,
                                    out + SL_OFF, out + ENT_OFF, out + REINF_OFF);
}

// Round 8
// 2580.104 us; speedup vs baseline: 1.1032x; 1.0722x over previous
//
#include <hip/hip_runtime.h>
#include <cstdint>
#include <cmath>

#define MASKV -9.0e20f

// ---------------- Threefry-2x32 (JAX-compatible) ----------------
__host__ __device__ inline void tf2x32(uint32_t k0, uint32_t k1, uint32_t& x0, uint32_t& x1){
  uint32_t ks2 = k0 ^ k1 ^ 0x1BD11BDAu;
  x0 += k0; x1 += k1;
#define TFR(r) { x0 += x1; x1 = (x1<<(r))|(x1>>(32-(r))); x1 ^= x0; }
  TFR(13) TFR(15) TFR(26) TFR(6)
  x0 += k1;  x1 += ks2 + 1u;
  TFR(17) TFR(29) TFR(16) TFR(24)
  x0 += ks2; x1 += k0 + 2u;
  TFR(13) TFR(15) TFR(26) TFR(6)
  x0 += k0;  x1 += k1 + 3u;
  TFR(17) TFR(29) TFR(16) TFR(24)
  x0 += k1;  x1 += ks2 + 4u;
  TFR(13) TFR(15) TFR(26) TFR(6)
  x0 += ks2; x1 += k0 + 5u;
#undef TFR
}

__device__ inline uint32_t rbits32(uint32_t k0, uint32_t k1, uint32_t idx){
  uint32_t x0 = 0u, x1 = idx;
  tf2x32(k0, k1, x0, x1);
  return x0 ^ x1;
}

__device__ inline float u01_from_bits(uint32_t bits){
  union { uint32_t u; float f; } c;
  c.u = (bits >> 9) | 0x3f800000u;
  return c.f - 1.0f;
}

__device__ inline float erfinv_f(float x){
  float w = -log1pf(-x*x);
  float p;
  if (w < 5.0f){
    w -= 2.5f;
    p = 2.81022636e-08f;
    p = fmaf(p, w, 3.43273939e-07f);
    p = fmaf(p, w, -3.5233877e-06f);
    p = fmaf(p, w, -4.39150654e-06f);
    p = fmaf(p, w, 0.00021858087f);
    p = fmaf(p, w, -0.00125372503f);
    p = fmaf(p, w, -0.00417768164f);
    p = fmaf(p, w, 0.246640727f);
    p = fmaf(p, w, 1.50140941f);
  } else {
    w = sqrtf(w) - 3.0f;
    p = -0.000200214257f;
    p = fmaf(p, w, 0.000100950558f);
    p = fmaf(p, w, 0.00134934322f);
    p = fmaf(p, w, -0.00367342844f);
    p = fmaf(p, w, 0.00573950773f);
    p = fmaf(p, w, -0.0076224613f);
    p = fmaf(p, w, 0.00943887047f);
    p = fmaf(p, w, 1.00167406f);
    p = fmaf(p, w, 2.83297682f);
  }
  return p * x;
}

__device__ inline float jax_normal(uint32_t k0, uint32_t k1, uint32_t idx){
  float f = u01_from_bits(rbits32(k0, k1, idx));
  float v = fmaf(f, 2.0f, -0.99999994f);
  v = fmaxf(v, -0.99999994f);
  return 1.41421356f * erfinv_f(v);
}

__device__ inline float jax_gumbel(uint32_t k0, uint32_t k1, uint32_t idx){
  float f = u01_from_bits(rbits32(k0, k1, idx));
  f = f + 1.17549435e-38f;
  f = fmaxf(f, 1.17549435e-38f);
  return -logf(-logf(f));
}

// ---------------- small tiled SGEMM (64x64 tile, 4x4 microtile) ----------------
template<int ACT>
__global__ __launch_bounds__(256) void gemm_k(
    const float* __restrict__ A, int lda,
    const long* __restrict__ atab, int anblk,
    const float* __restrict__ W, const float* __restrict__ bias,
    float* __restrict__ C, int K, int N,
    long c_base, int c_rdiv, long c_ostride, long c_istride)
{
  __shared__ float As[16][64];
  __shared__ float Ws[16][64];
  int tid = threadIdx.x;
  int c0 = blockIdx.x * 64;
  int r0 = blockIdx.y * 64;
  int lr = tid >> 2;
  int lk = (tid & 3) << 2;
  int wk = tid >> 4;
  int wc = (tid & 15) << 2;
  int tx = tid & 15;
  int ty = tid >> 4;
  long aoff0 = 0, aoff1 = 0;
  if (atab){
    const long* t = atab + (long)(r0 + lr) * anblk;
    aoff0 = t[0];
    if (anblk == 2) aoff1 = t[1];
  } else {
    aoff0 = (long)(r0 + lr) * lda;
  }
  float acc[4][4];
#pragma unroll
  for (int i = 0; i < 4; i++)
#pragma unroll
    for (int j = 0; j < 4; j++) acc[i][j] = 0.f;

  for (int k0 = 0; k0 < K; k0 += 16){
    int ka = k0 + lk;
    long ab = (atab && anblk == 2 && ka >= 512) ? (aoff1 + (ka - 512)) : (aoff0 + ka);
    float4 av = *(const float4*)(A + ab);
    As[lk + 0][lr] = av.x;
    As[lk + 1][lr] = av.y;
    As[lk + 2][lr] = av.z;
    As[lk + 3][lr] = av.w;
    float4 wv = *(const float4*)(W + (long)(k0 + wk) * N + (c0 + wc));
    *(float4*)&Ws[wk][wc] = wv;
    __syncthreads();
#pragma unroll
    for (int kk = 0; kk < 16; kk++){
      float4 a4 = *(const float4*)&As[kk][ty << 2];
      float4 w4 = *(const float4*)&Ws[kk][tx << 2];
      float aa[4] = {a4.x, a4.y, a4.z, a4.w};
      float ww[4] = {w4.x, w4.y, w4.z, w4.w};
#pragma unroll
      for (int i = 0; i < 4; i++)
#pragma unroll
        for (int j = 0; j < 4; j++)
          acc[i][j] = fmaf(aa[i], ww[j], acc[i][j]);
    }
    __syncthreads();
  }
  float4 bv = *(const float4*)(bias + c0 + (tx << 2));
  float bb[4] = {bv.x, bv.y, bv.z, bv.w};
#pragma unroll
  for (int i = 0; i < 4; i++){
    int r = r0 + (ty << 2) + i;
    long off = c_base + (long)(r / c_rdiv) * c_ostride + (long)(r % c_rdiv) * c_istride
               + c0 + (tx << 2);
    float4 v;
    float o0 = acc[i][0] + bb[0], o1 = acc[i][1] + bb[1];
    float o2 = acc[i][2] + bb[2], o3 = acc[i][3] + bb[3];
    if (ACT){ o0 = fmaxf(o0, 0.f); o1 = fmaxf(o1, 0.f); o2 = fmaxf(o2, 0.f); o3 = fmaxf(o3, 0.f); }
    v.x = o0; v.y = o1; v.z = o2; v.w = o3;
    *(float4*)(C + off) = v;
  }
}

// ---------------- 128-tile fused policy GEMM (initial step, 30720 rows) ----------------
// microtile = 2x(4 rows) x 2x(4 cols), halves 64 apart -> conflict-free LDS reads
__global__ __launch_bounds__(256) void gemm128f_k(
    const float* __restrict__ Y,
    const long* __restrict__ atab,
    const float* __restrict__ b1,
    const float* __restrict__ W2, const float* __restrict__ b2,
    const float* __restrict__ w3,
    const int* __restrict__ scat, float* __restrict__ logits)
{
  __shared__ float As[16][132];
  __shared__ float Ws[16][132];
  int tid = threadIdx.x;
  int c0 = blockIdx.x * 128;
  int r0 = blockIdx.y * 128;
  int tx = tid & 15, ty = tid >> 4;
  int rA0 = tid >> 2;
  int rA1 = rA0 + 64;
  int kq = (tid & 3) << 2;
  long a00 = atab[(long)(r0 + rA0) * 2];
  long a01 = atab[(long)(r0 + rA0) * 2 + 1];
  long a10 = atab[(long)(r0 + rA1) * 2];
  long a11 = atab[(long)(r0 + rA1) * 2 + 1];
  int wk0 = tid >> 5, wc0 = (tid & 31) << 2;
  float acc[8][8];
#pragma unroll
  for (int i = 0; i < 8; i++)
#pragma unroll
    for (int j = 0; j < 8; j++) acc[i][j] = 0.f;

  for (int k0 = 0; k0 < 512; k0 += 16){
    int ka = k0 + kq;
    float4 p0 = *(const float4*)(Y + a00 + ka);
    float4 q0 = *(const float4*)(Y + a01 + ka);
    float4 p1 = *(const float4*)(Y + a10 + ka);
    float4 q1 = *(const float4*)(Y + a11 + ka);
    float4 bb = *(const float4*)(b1 + ka);
    As[kq + 0][rA0] = fmaxf(p0.x + q0.x + bb.x, 0.f);
    As[kq + 1][rA0] = fmaxf(p0.y + q0.y + bb.y, 0.f);
    As[kq + 2][rA0] = fmaxf(p0.z + q0.z + bb.z, 0.f);
    As[kq + 3][rA0] = fmaxf(p0.w + q0.w + bb.w, 0.f);
    As[kq + 0][rA1] = fmaxf(p1.x + q1.x + bb.x, 0.f);
    As[kq + 1][rA1] = fmaxf(p1.y + q1.y + bb.y, 0.f);
    As[kq + 2][rA1] = fmaxf(p1.z + q1.z + bb.z, 0.f);
    As[kq + 3][rA1] = fmaxf(p1.w + q1.w + bb.w, 0.f);
    *(float4*)&Ws[wk0][wc0]     = *(const float4*)(W2 + (long)(k0 + wk0) * 512 + (c0 + wc0));
    *(float4*)&Ws[wk0 + 8][wc0] = *(const float4*)(W2 + (long)(k0 + wk0 + 8) * 512 + (c0 + wc0));
    __syncthreads();
#pragma unroll
    for (int kk = 0; kk < 16; kk++){
      float a0[8], w0[8];
      *(float4*)&a0[0] = *(const float4*)&As[kk][ty << 2];
      *(float4*)&a0[4] = *(const float4*)&As[kk][(ty << 2) + 64];
      *(float4*)&w0[0] = *(const float4*)&Ws[kk][tx << 2];
      *(float4*)&w0[4] = *(const float4*)&Ws[kk][(tx << 2) + 64];
#pragma unroll
      for (int i = 0; i < 8; i++)
#pragma unroll
        for (int j = 0; j < 8; j++)
          acc[i][j] = fmaf(a0[i], w0[j], acc[i][j]);
    }
    __syncthreads();
  }
  float bb[8], w3v[8];
  *(float4*)&bb[0]  = *(const float4*)(b2 + c0 + (tx << 2));
  *(float4*)&bb[4]  = *(const float4*)(b2 + c0 + (tx << 2) + 64);
  *(float4*)&w3v[0] = *(const float4*)(w3 + c0 + (tx << 2));
  *(float4*)&w3v[4] = *(const float4*)(w3 + c0 + (tx << 2) + 64);
#pragma unroll
  for (int i = 0; i < 8; i++){
    float p = 0.f;
#pragma unroll
    for (int j = 0; j < 8; j++)
      p = fmaf(fmaxf(acc[i][j] + bb[j], 0.f), w3v[j], p);
    for (int m = 1; m < 16; m <<= 1) p += __shfl_xor(p, m);
    if (tx == 0){
      int rr = (i < 4) ? ((ty << 2) + i) : (64 + (ty << 2) + (i - 4));
      atomicAdd(logits + scat[r0 + rr], p);
    }
  }
}

// ---------------- 64-tile fused policy GEMM (in-loop, rows <= 3584) ----------------
__global__ __launch_bounds__(256) void gemm64f_k(
    const float* __restrict__ Y,
    const long* __restrict__ atab,
    const float* __restrict__ b1,
    const float* __restrict__ W2, const float* __restrict__ b2,
    const float* __restrict__ w3,
    const int* __restrict__ scat, float* __restrict__ logits)
{
  __shared__ float As[16][64];
  __shared__ float Ws[16][64];
  int tid = threadIdx.x;
  int c0 = blockIdx.x * 64;
  int r0 = blockIdx.y * 64;
  int lr = tid >> 2;
  int lk = (tid & 3) << 2;
  int wk = tid >> 4;
  int wc = (tid & 15) << 2;
  int tx = tid & 15;
  int ty = tid >> 4;
  long a0 = atab[(long)(r0 + lr) * 2];
  long a1 = atab[(long)(r0 + lr) * 2 + 1];
  float acc[4][4];
#pragma unroll
  for (int i = 0; i < 4; i++)
#pragma unroll
    for (int j = 0; j < 4; j++) acc[i][j] = 0.f;

  for (int k0 = 0; k0 < 512; k0 += 16){
    int ka = k0 + lk;
    float4 p = *(const float4*)(Y + a0 + ka);
    float4 q = *(const float4*)(Y + a1 + ka);
    float4 bb = *(const float4*)(b1 + ka);
    As[lk + 0][lr] = fmaxf(p.x + q.x + bb.x, 0.f);
    As[lk + 1][lr] = fmaxf(p.y + q.y + bb.y, 0.f);
    As[lk + 2][lr] = fmaxf(p.z + q.z + bb.z, 0.f);
    As[lk + 3][lr] = fmaxf(p.w + q.w + bb.w, 0.f);
    *(float4*)&Ws[wk][wc] = *(const float4*)(W2 + (long)(k0 + wk) * 512 + (c0 + wc));
    __syncthreads();
#pragma unroll
    for (int kk = 0; kk < 16; kk++){
      float4 a4 = *(const float4*)&As[kk][ty << 2];
      float4 w4 = *(const float4*)&Ws[kk][tx << 2];
      float aa[4] = {a4.x, a4.y, a4.z, a4.w};
      float ww[4] = {w4.x, w4.y, w4.z, w4.w};
#pragma unroll
      for (int i = 0; i < 4; i++)
#pragma unroll
        for (int j = 0; j < 4; j++)
          acc[i][j] = fmaf(aa[i], ww[j], acc[i][j]);
    }
    __syncthreads();
  }
  float bb4[4], w34[4];
  *(float4*)&bb4[0] = *(const float4*)(b2 + c0 + (tx << 2));
  *(float4*)&w34[0] = *(const float4*)(w3 + c0 + (tx << 2));
#pragma unroll
  for (int i = 0; i < 4; i++){
    float p = 0.f;
#pragma unroll
    for (int j = 0; j < 4; j++)
      p = fmaf(fmaxf(acc[i][j] + bb4[j], 0.f), w34[j], p);
    for (int m = 1; m < 16; m <<= 1) p += __shfl_xor(p, m);
    if (tx == 0){
      int r = r0 + (ty << 2) + i;
      atomicAdd(logits + scat[r], p);
    }
  }
}

// N=2 final layer with scatter table: one wave per row
__global__ __launch_bounds__(256) void rowdot2_k(
    const float* __restrict__ A, int lda,
    const float* __restrict__ W, const float* __restrict__ bias,
    int K, float* __restrict__ out, const int* __restrict__ scat)
{
  int wid = threadIdx.x >> 6, lane = threadIdx.x & 63;
  int r = blockIdx.x * 4 + wid;
  const float* a = A + (long)r * lda;
  float s0 = 0.f, s1 = 0.f;
  for (int k = lane; k < K; k += 64){
    float x = a[k];
    s0 = fmaf(x, W[k * 2], s0);
    s1 = fmaf(x, W[k * 2 + 1], s1);
  }
  for (int off = 32; off > 0; off >>= 1){
    s0 += __shfl_down(s0, off);
    s1 += __shfl_down(s1, off);
  }
  if (lane == 0){
    long o = scat[r];
    out[o] = s0 + bias[0];
    out[o + 1] = s1 + bias[1];
  }
}

// ---------------- wide per-layer matvec kernels (row/block, col/thread) ----------------
// enc layer1: src = pair gather (K=1024), C=512, relu. grid (2, 128)
__global__ __launch_bounds__(256) void pairmv_k(
    const float* __restrict__ u, const long* __restrict__ tab_pair,
    const float* __restrict__ W, const float* __restrict__ bias,
    float* __restrict__ dst)
{
  __shared__ float s[1024];
  int b = blockIdx.y, tid = threadIdx.x;
  int c = blockIdx.x * 256 + tid;
  long t0 = tab_pair[b * 2], t1 = tab_pair[b * 2 + 1];
  s[tid]       = u[t0 + tid];
  s[tid + 256] = u[t0 + tid + 256];
  s[tid + 512] = u[t1 + tid];
  s[tid + 768] = u[t1 + tid + 256];
  __syncthreads();
  float a0 = 0.f, a1 = 0.f, a2 = 0.f, a3 = 0.f;
#pragma unroll 8
  for (int k = 0; k < 1024; k += 4){
    a0 = fmaf(s[k],     W[(long)k * 512 + c],       a0);
    a1 = fmaf(s[k + 1], W[(long)(k + 1) * 512 + c], a1);
    a2 = fmaf(s[k + 2], W[(long)(k + 2) * 512 + c], a2);
    a3 = fmaf(s[k + 3], W[(long)(k + 3) * 512 + c], a3);
  }
  float v = ((a0 + a1) + (a2 + a3)) + bias[c];
  dst[(long)b * 512 + c] = fmaxf(v, 0.f);
}

// generic K=512 -> C=512 relu layer. grid (2, 128)
__global__ __launch_bounds__(256) void mvrelu_k(
    const float* __restrict__ src, long sstride,
    const float* __restrict__ W, const float* __restrict__ bias,
    float* __restrict__ dst)
{
  __shared__ float s[512];
  int b = blockIdx.y, tid = threadIdx.x;
  int c = blockIdx.x * 256 + tid;
  const float* sr = src + (long)b * sstride;
  s[tid] = sr[tid];
  s[tid + 256] = sr[tid + 256];
  __syncthreads();
  float a0 = 0.f, a1 = 0.f, a2 = 0.f, a3 = 0.f;
#pragma unroll 8
  for (int k = 0; k < 512; k += 4){
    a0 = fmaf(s[k],     W[(long)k * 512 + c],       a0);
    a1 = fmaf(s[k + 1], W[(long)(k + 1) * 512 + c], a1);
    a2 = fmaf(s[k + 2], W[(long)(k + 2) * 512 + c], a2);
    a3 = fmaf(s[k + 3], W[(long)(k + 3) * 512 + c], a3);
  }
  float v = ((a0 + a1) + (a2 + a3)) + bias[c];
  dst[(long)b * 512 + c] = fmaxf(v, 0.f);
}

// enc layer3: z = h2@W + b (no relu); store z, and u token row = z + noise. grid (2, 128)
__global__ __launch_bounds__(256) void lay3z_k(
    const float* __restrict__ src,
    const float* __restrict__ W, const float* __restrict__ bias,
    float* __restrict__ z_all, float* __restrict__ u,
    int it, uint32_t k0, uint32_t k1)
{
  __shared__ float s[512];
  int b = blockIdx.y, tid = threadIdx.x;
  int c = blockIdx.x * 256 + tid;
  const float* sr = src + (long)b * 512;
  s[tid] = sr[tid];
  s[tid + 256] = sr[tid + 256];
  __syncthreads();
  float a0 = 0.f, a1 = 0.f, a2 = 0.f, a3 = 0.f;
#pragma unroll 8
  for (int k = 0; k < 512; k += 4){
    a0 = fmaf(s[k],     W[(long)k * 512 + c],       a0);
    a1 = fmaf(s[k + 1], W[(long)(k + 1) * 512 + c], a1);
    a2 = fmaf(s[k + 2], W[(long)(k + 2) * 512 + c], a2);
    a3 = fmaf(s[k + 3], W[(long)(k + 3) * 512 + c], a3);
  }
  float v = ((a0 + a1) + (a2 + a3)) + bias[c];
  z_all[(long)it * 65536 + (long)b * 512 + c] = v;
  float nv = jax_normal(k0, k1, (uint32_t)(b * 512 + c));
  u[((long)(b * 31 + 16 + it)) * 512 + c] = v + 0.01f * nv;
}

// Y row for new token: Y[tok] = u[tok] @ W1cat (no bias). grid (4, 128)
__global__ __launch_bounds__(256) void yrow_k(
    const float* __restrict__ u, const float* __restrict__ W1cat,
    float* __restrict__ Y, int it)
{
  __shared__ float s[512];
  int b = blockIdx.y, tid = threadIdx.x;
  int c = blockIdx.x * 256 + tid;
  const float* sr = u + ((long)(b * 31 + 16 + it)) * 512;
  s[tid] = sr[tid];
  s[tid + 256] = sr[tid + 256];
  __syncthreads();
  float a0 = 0.f, a1 = 0.f, a2 = 0.f, a3 = 0.f;
#pragma unroll 8
  for (int k = 0; k < 512; k += 4){
    a0 = fmaf(s[k],     W1cat[(long)k * 1024 + c],       a0);
    a1 = fmaf(s[k + 1], W1cat[(long)(k + 1) * 1024 + c], a1);
    a2 = fmaf(s[k + 2], W1cat[(long)(k + 2) * 1024 + c], a2);
    a3 = fmaf(s[k + 3], W1cat[(long)(k + 3) * 1024 + c], a3);
  }
  Y[((long)(b * 31 + 16 + it)) * 1024 + c] = (a0 + a1) + (a2 + a3);
}

// reverse layer3 + scatter into dmat. grid (4, 128)
__global__ __launch_bounds__(256) void rev3_k(
    const float* __restrict__ src,
    const float* __restrict__ W, const float* __restrict__ bias,
    float* __restrict__ dmat, const int* __restrict__ actions, int it)
{
  __shared__ float s[512];
  int b = blockIdx.y, tid = threadIdx.x;
  int p = blockIdx.x * 256 + tid;
  const float* sr = src + (long)b * 512;
  s[tid] = sr[tid];
  s[tid + 256] = sr[tid + 256];
  __syncthreads();
  float a0 = 0.f, a1 = 0.f, a2 = 0.f, a3 = 0.f;
#pragma unroll 8
  for (int k = 0; k < 512; k += 4){
    a0 = fmaf(s[k],     W[(long)k * 1024 + p],       a0);
    a1 = fmaf(s[k + 1], W[(long)(k + 1) * 1024 + p], a1);
    a2 = fmaf(s[k + 2], W[(long)(k + 2) * 1024 + p], a2);
    a3 = fmaf(s[k + 3], W[(long)(k + 3) * 1024 + p], a3);
  }
  float v = ((a0 + a1) + (a2 + a3)) + bias[p];
  int fit = 14 - it;
  int s0 = actions[(b * 15 + fit) * 2];
  int s1 = actions[(b * 15 + fit) * 2 + 1];
  int node = (p < 512) ? s0 : s1;
  int ee = p & 511;
  dmat[((long)(b * 31 + node)) * 512 + ee] = v;
}

// batched osl over all steps: grid 1920 (r = it*128 + b)
__global__ __launch_bounds__(256) void oslb_k(
    const float* __restrict__ pred, const float* __restrict__ u,
    const int* __restrict__ actions, float* __restrict__ sl, float* __restrict__ rew)
{
  int r = blockIdx.x, tid = threadIdx.x;
  int it = r >> 7, b = r & 127;
  int s0 = actions[(b * 15 + it) * 2];
  int s1 = actions[(b * 15 + it) * 2 + 1];
  const float* t0 = u + ((long)(b * 31 + s0)) * 512;
  const float* t1 = u + ((long)(b * 31 + s1)) * 512;
  const float* p = pred + (long)r * 1024;
  float s = 0.f;
  for (int k = tid; k < 512; k += 256){
    float d0 = p[k] - t0[k];       s = fmaf(d0, d0, s);
    float d1 = p[k + 512] - t1[k]; s = fmaf(d1, d1, s);
  }
  __shared__ float red[256];
  red[tid] = s; __syncthreads();
  for (int st = 128; st > 0; st >>= 1){ if (tid < st) red[tid] += red[tid + st]; __syncthreads(); }
  if (tid == 0){
    float osl = red[0] / 1024.0f;
    atomicAdd(sl + b, osl);
    rew[b * 15 + it] = -osl;
  }
}

// ---------------- init (no dmat zeroing: every cell of d is provably overwritten) ----------------
__global__ __launch_bounds__(256) void init_k(float* __restrict__ lbl,
    float* __restrict__ logits, float* __restrict__ sl, float* __restrict__ ent,
    int* __restrict__ active, float* __restrict__ zb,
    float* __restrict__ W1cat, const float* __restrict__ pol_w1, const float* __restrict__ pol_b3,
    long* __restrict__ tab_init, int* __restrict__ scat_init, long* __restrict__ tab_tok16,
    long* __restrict__ tab_mgd, int* __restrict__ scat_clf, long clf_off)
{
  long i = (long)blockIdx.x * 256 + threadIdx.x;
  if (i < 524288L){
    int k = (int)(i >> 10), n = (int)(i & 1023);
    W1cat[i] = (n < 512) ? pol_w1[(long)k * 512 + n] : pol_w1[(long)(k + 512) * 512 + (n - 512)];
  }
  if (i < 115200L){
    int rem = (int)(i % 900);
    int rr = rem / 30, cc = rem % 30;
    logits[i] = (rr < 16 && cc < 16 && rr != cc) ? pol_b3[0] : MASKV;
  }
  if (i < 30720L){
    int r = (int)i;
    int pk = r >> 7, b = r & 127;
    int ii2 = pk / 15, jr = pk % 15;
    int jj2 = jr + (jr >= ii2 ? 1 : 0);
    tab_init[r * 2]     = ((long)(b * 31 + ii2)) * 1024;
    tab_init[r * 2 + 1] = ((long)(b * 31 + jj2)) * 1024 + 512;
    scat_init[r] = b * 900 + ii2 * 30 + jj2;
  }
  if (i < 3968L){
    lbl[i] = ((i % 31) < 15) ? 1.0f : 0.0f;
    int r = (int)i;
    if (r < 1920){
      scat_clf[r] = (int)(clf_off + (long)(r & 127) * 62 + (r >> 7) * 2);
    } else {
      int rr = r - 1920;
      scat_clf[r] = (int)(clf_off + (long)(rr >> 4) * 62 + 60 - ((rr & 15) << 1));
    }
  }
  if (i < 2048L){
    active[i] = (int)(i & 15);
    tab_tok16[i] = ((long)((i >> 4) * 31 + (i & 15))) * 512;
  }
  if (i < 1920L){
    int it = (int)(i >> 7), b = (int)(i & 127);
    tab_mgd[i] = ((long)(b * 31 + 30 - it)) * 512;
  }
  if (i < 1024L)  zb[i] = 0.f;
  if (i < 128L){ sl[i] = 0.f; ent[i] = 0.f; }
}

__global__ __launch_bounds__(256) void noise_u_k(float* __restrict__ u, uint32_t k0, uint32_t k1){
  uint32_t e = blockIdx.x * 256u + threadIdx.x; // < 1048576
  uint32_t b = e >> 13, rem = e & 8191u, n = rem >> 9, ee = rem & 511u;
  float nr = jax_normal(k0, k1, e);
  long off = ((long)(b * 31u + n)) * 512 + ee;
  u[off] += 0.01f * nr;
}

__global__ __launch_bounds__(256) void build_d_k(float* __restrict__ dmat, const float* __restrict__ u){
  int e = blockIdx.x * 256 + threadIdx.x; // 65536
  int b = e >> 9, ee = e & 511;
  long off = ((long)(b * 31 + 30)) * 512 + ee;
  dmat[off] = u[off];
}

// softmax stats + entropy + gumbel-argmax + mask + active update + next tables + b3 preset
__global__ __launch_bounds__(256) void sample_k(float* __restrict__ logits, int* __restrict__ active,
    int* __restrict__ actions, float* __restrict__ lp, float* __restrict__ ent,
    int it, int A, uint32_t k0, uint32_t k1, float log_opt,
    long* __restrict__ tab_loop, int* __restrict__ scat_loop, long* __restrict__ tab_pair,
    const float* __restrict__ pol_b3)
{
  int b = blockIdx.x, tid = threadIdx.x;
  float* Lg = logits + (long)b * 900;
  __shared__ float red[256];
  __shared__ int redi[256];
  __shared__ int ss0, ss1;

  float v = -3.4e38f;
  for (int j = tid; j < 900; j += 256) v = fmaxf(v, Lg[j]);
  red[tid] = v; __syncthreads();
  for (int s = 128; s > 0; s >>= 1){ if (tid < s) red[tid] = fmaxf(red[tid], red[tid + s]); __syncthreads(); }
  float m = red[0]; __syncthreads();

  float acc = 0.f;
  for (int j = tid; j < 900; j += 256) acc += expf(Lg[j] - m);
  red[tid] = acc; __syncthreads();
  for (int s = 128; s > 0; s >>= 1){ if (tid < s) red[tid] += red[tid + s]; __syncthreads(); }
  float ssum = red[0]; __syncthreads();

  float es = 0.f;
  for (int j = tid; j < 900; j += 256){
    float l = Lg[j];
    if (l > MASKV){
      float p = expf(l - m) / ssum;
      float pa = p + 1e-20f;
      es += pa * logf(pa);
    }
  }
  red[tid] = es; __syncthreads();
  for (int s = 128; s > 0; s >>= 1){ if (tid < s) red[tid] += red[tid + s]; __syncthreads(); }
  if (tid == 0) ent[b] += -(red[0]) / log_opt;
  __syncthreads();

  float bv = -3.4e38f; int bi = 0;
  for (int j = tid; j < 900; j += 256){
    float g = jax_gumbel(k0, k1, (uint32_t)(b * 900 + j));
    float val = Lg[j] + g;
    if (val > bv){ bv = val; bi = j; }
  }
  red[tid] = bv; redi[tid] = bi; __syncthreads();
  for (int s = 128; s > 0; s >>= 1){
    if (tid < s){
      float o = red[tid + s]; int oi = redi[tid + s];
      if (o > red[tid] || (o == red[tid] && oi < redi[tid])){ red[tid] = o; redi[tid] = oi; }
    }
    __syncthreads();
  }
  if (tid == 0){
    int sf = redi[0];
    int s0 = sf / 30, s1 = sf % 30;
    ss0 = s0; ss1 = s1;
    actions[(b * 15 + it) * 2] = s0;
    actions[(b * 15 + it) * 2 + 1] = s1;
    lp[b * 15 + it] = Lg[sf] - m - logf(ssum);
    tab_pair[b * 2]     = ((long)(b * 31 + s0)) * 512;
    tab_pair[b * 2 + 1] = ((long)(b * 31 + s1)) * 512;
  }
  __syncthreads();
  int s0 = ss0, s1 = ss1;
  if (tid < 30){
    Lg[s0 * 30 + tid] = MASKV;
    Lg[s1 * 30 + tid] = MASKV;
    Lg[tid * 30 + s0] = MASKV;
    Lg[tid * 30 + s1] = MASKV;
  }
  if (tid == 0){
    float b3v = pol_b3[0];
    int buf[16]; int c = 0;
    for (int k = 0; k < A; k++){
      int a = active[b * 16 + k];
      if (a != s0 && a != s1) buf[c++] = a;
    }
    int nt2 = 16 + it;
    buf[c++] = nt2;
    for (int k = 0; k < c; k++) active[b * 16 + k] = buf[k];
    int na2 = c - 1;
    for (int j = 0; j < na2; j++){
      int q = buf[j];
      int r1 = j * 128 + b;
      tab_loop[r1 * 2]     = ((long)(b * 31 + nt2)) * 1024;
      tab_loop[r1 * 2 + 1] = ((long)(b * 31 + q)) * 1024 + 512;
      int sc1 = b * 900 + nt2 * 30 + q;
      scat_loop[r1] = sc1;
      logits[sc1] = b3v;
      int r2 = (na2 + j) * 128 + b;
      tab_loop[r2 * 2]     = ((long)(b * 31 + q)) * 1024;
      tab_loop[r2 * 2 + 1] = ((long)(b * 31 + nt2)) * 1024 + 512;
      int sc2 = b * 900 + q * 30 + nt2;
      scat_loop[r2] = sc2;
      logits[sc2] = b3v;
    }
  }
}

__global__ __launch_bounds__(256) void finalize_k(const float* __restrict__ rew,
    const float* __restrict__ lp, const float* __restrict__ sl, const float* __restrict__ ent,
    float* __restrict__ out_sl, float* __restrict__ out_ent, float* __restrict__ out_reinf)
{
  __shared__ float red[256];
  int tid = threadIdx.x;
  float s = 0.f;
  for (int i = tid; i < 1920; i += 256) s += rew[i];
  red[tid] = s; __syncthreads();
  for (int st = 128; st > 0; st >>= 1){ if (tid < st) red[tid] += red[tid + st]; __syncthreads(); }
  float mean = red[0] / 1920.0f; __syncthreads();
  float v = 0.f;
  for (int i = tid; i < 1920; i += 256){ float x = rew[i] - mean; v = fmaf(x, x, v); }
  red[tid] = v; __syncthreads();
  for (int st = 128; st > 0; st >>= 1){ if (tid < st) red[tid] += red[tid + st]; __syncthreads(); }
  float denom = sqrtf(red[0] / 1919.0f) + 1e-20f;
  if (tid < 128){
    out_sl[tid] = sl[tid] / 15.0f;
    out_ent[tid] = ent[tid] / 15.0f;
    float r = 0.f;
    for (int k = 0; k < 15; k++){
      float rn = (rew[tid * 15 + k] - mean) / denom;
      r = fmaf(lp[tid * 15 + k], rn, r);
    }
    out_reinf[tid] = r;
  }
}

// ---------------- host ----------------
extern "C" void kernel_launch(void* const* d_in, const int* in_sizes, int n_in,
                              void* d_out, int out_size, void* d_ws, size_t ws_size,
                              hipStream_t stream)
{
  const float* x        = (const float*)d_in[0];
  const float* lift_w   = (const float*)d_in[1];
  const float* lift_b   = (const float*)d_in[2];
  const float* unlift_w = (const float*)d_in[3];
  const float* unlift_b = (const float*)d_in[4];
  const float* enc_w1   = (const float*)d_in[5];
  const float* enc_b1   = (const float*)d_in[6];
  const float* enc_w2   = (const float*)d_in[7];
  const float* enc_b2   = (const float*)d_in[8];
  const float* enc_w3   = (const float*)d_in[9];
  const float* enc_b3   = (const float*)d_in[10];
  const float* dec_w1   = (const float*)d_in[11];
  const float* dec_b1   = (const float*)d_in[12];
  const float* dec_w2   = (const float*)d_in[13];
  const float* dec_b2   = (const float*)d_in[14];
  const float* dec_w3   = (const float*)d_in[15];
  const float* dec_b3   = (const float*)d_in[16];
  const float* clf_w1   = (const float*)d_in[17];
  const float* clf_b1   = (const float*)d_in[18];
  const float* clf_w2   = (const float*)d_in[19];
  const float* clf_b2   = (const float*)d_in[20];
  const float* clf_w3   = (const float*)d_in[21];
  const float* clf_b3   = (const float*)d_in[22];
  const float* pol_w1   = (const float*)d_in[23];
  const float* pol_b1   = (const float*)d_in[24];
  const float* pol_w2   = (const float*)d_in[25];
  const float* pol_b2   = (const float*)d_in[26];
  const float* pol_w3   = (const float*)d_in[27];
  const float* pol_b3   = (const float*)d_in[28];

  float* out = (float*)d_out;
  const long U_OFF     = 2097152;
  const long D_OFF     = 4128768;
  const long SL_OFF    = 6160384;
  const long ENT_OFF   = 6160512;
  const long CLF_OFF   = 6160640;
  const long LBL_OFF   = 6168576;
  const long REINF_OFF = 6172544;
  float* recon = out;
  float* u     = out + U_OFF;
  float* dmat  = out + D_OFF;

  char* wsb = (char*)d_ws;
  size_t wo = 0;
  auto alloc = [&](size_t bytes) -> void* {
    void* p = (void*)(wsb + wo);
    wo = (wo + bytes + 255) & ~(size_t)255;
    return p;
  };
  float* logits    = (float*)alloc(115200 * 4);
  float* Y         = (float*)alloc((size_t)3968 * 1024 * 4); // dead after fwd -> overlays:
  float* h1clf     = Y;                  // tail clf hidden1 (3968x512)
  float* pbuf      = Y + 2031616;        // dec output 1920x1024, then clf h2
  float* h2clf     = Y + 2031616;
  float* W1cat     = (float*)alloc((size_t)524288 * 4);
  float* zb        = (float*)alloc(1024 * 4);
  float* h1        = (float*)alloc((size_t)2048 * 512 * 4);
  float* h2        = (float*)alloc((size_t)2048 * 512 * 4);
  float* z_all     = (float*)alloc((size_t)15 * 65536 * 4);
  float* sl        = (float*)alloc(128 * 4);
  float* ent       = (float*)alloc(128 * 4);
  float* lp        = (float*)alloc(1920 * 4);
  float* rew       = (float*)alloc(1920 * 4);
  int*   active    = (int*)alloc(2048 * 4);
  int*   actions   = (int*)alloc(3840 * 4);
  long*  tab_init  = (long*)alloc((size_t)30720 * 2 * 8);
  int*   scat_init = (int*)alloc(30720 * 4);
  long*  tab_loop  = (long*)alloc((size_t)3584 * 2 * 8);
  int*   scat_loop = (int*)alloc(3584 * 4);
  long*  tab_pair  = (long*)alloc(256 * 8);
  long*  tab_mgd   = (long*)alloc(1920 * 8);   // contiguous with tab_tok16 -> 3968-row clf table
  long*  tab_tok16 = (long*)alloc(2048 * 8);
  int*   scat_clf  = (int*)alloc(3968 * 4);
  long*  tab_clf   = tab_mgd;
  (void)ws_size; (void)in_sizes; (void)n_in; (void)out_size;

  uint32_t k7a, k7b, ck0[15], ck1[15], mk0[15], mk1[15];
  { uint32_t a = 0, b = 7; tf2x32(0u, 42u, a, b); k7a = a; k7b = b; }
  for (int it = 0; it < 15; it++){
    { uint32_t a = 0, b = (uint32_t)(100 + it); tf2x32(0u, 42u, a, b); ck0[it] = a; ck1[it] = b; }
    { uint32_t a = 0, b = (uint32_t)(1000 + it); tf2x32(0u, 42u, a, b); mk0[it] = a; mk1[it] = b; }
  }

  auto gemm = [&](int act, const float* A, int lda, const long* atab, int anblk,
                  const float* W, const float* bs, float* C, int rows, int K, int Nn,
                  long cb, int crd, long cos, long cis){
    dim3 g(Nn / 64, rows / 64);
    if (act) gemm_k<1><<<g, 256, 0, stream>>>(A, lda, atab, anblk, W, bs, C, K, Nn, cb, crd, cos, cis);
    else     gemm_k<0><<<g, 256, 0, stream>>>(A, lda, atab, anblk, W, bs, C, K, Nn, cb, crd, cos, cis);
  };

  // ---- init ----
  init_k<<<2048, 256, 0, stream>>>(out + LBL_OFF, logits, sl, ent, active, zb,
                                   W1cat, pol_w1, pol_b3, tab_init, scat_init, tab_tok16,
                                   tab_mgd, scat_clf, CLF_OFF);

  // ---- lift + noise ----
  gemm(0, x, 1024, nullptr, 0, lift_w, lift_b, u, 2048, 1024, 512, 0, 16, 15872, 512);
  noise_u_k<<<4096, 256, 0, stream>>>(u, k7a, k7b);

  // ---- Y init for tokens 0..15 ----
  gemm(0, u, 0, tab_tok16, 1, W1cat, zb, Y, 2048, 512, 1024, 0, 16, 31744, 1024);

  // ---- initial policy logits ----
  { dim3 g(4, 240);
    gemm128f_k<<<g, 256, 0, stream>>>(Y, tab_init, pol_b1, pol_w2, pol_b2, pol_w3,
                                      scat_init, logits); }

  // ---- forward merge loop (R4 shape: dec deferred, 5-6 kernels/iter) ----
  for (int it = 0; it < 15; it++){
    int A = 16 - it;
    if (it > 0){
      int rows = 256 * (15 - it);
      dim3 g(8, rows / 64);
      gemm64f_k<<<g, 256, 0, stream>>>(Y, tab_loop, pol_b1, pol_w2, pol_b2, pol_w3,
                                       scat_loop, logits);
    }
    float log_opt = (float)log((double)(A * (A - 1)));
    sample_k<<<128, 256, 0, stream>>>(logits, active, actions, lp, ent, it, A,
                                      ck0[it], ck1[it], log_opt,
                                      tab_loop, scat_loop, tab_pair, pol_b3);
    { dim3 g(2, 128);
      pairmv_k<<<g, 256, 0, stream>>>(u, tab_pair, enc_w1, enc_b1, h1); }
    { dim3 g(2, 128);
      mvrelu_k<<<g, 256, 0, stream>>>(h1, 512, enc_w2, enc_b2, h2); }
    { dim3 g(2, 128);
      lay3z_k<<<g, 256, 0, stream>>>(h2, enc_w3, enc_b3, z_all, u, it, mk0[it], mk1[it]); }
    if (it < 14){
      dim3 g(4, 128);
      yrow_k<<<g, 256, 0, stream>>>(u, W1cat, Y, it);
    }
  }

  // ---- deferred batched dec over all 15 steps (1920 rows), then osl ----
  gemm(1, z_all, 512, nullptr, 0, dec_w1, dec_b1, h1, 1920, 512, 512, 0, 1, 512, 0);
  gemm(1, h1, 512, nullptr, 0, dec_w2, dec_b2, h2, 1920, 512, 512, 0, 1, 512, 0);
  gemm(0, h2, 512, nullptr, 0, dec_w3, dec_b3, pbuf, 1920, 512, 1024, 0, 1, 1024, 0);
  oslb_k<<<1920, 256, 0, stream>>>(pbuf, u, actions, sl, rew);

  // ---- d init (only token 30 active) ----
  build_d_k<<<256, 256, 0, stream>>>(dmat, u);

  // ---- reverse unmerge loop (R4 shape): 3 wide layers per step ----
  for (int it = 0; it < 15; it++){
    int tok = 30 - it;
    { dim3 g(2, 128);
      mvrelu_k<<<g, 256, 0, stream>>>(dmat + (long)tok * 512, 15872, dec_w1, dec_b1, h1); }
    { dim3 g(2, 128);
      mvrelu_k<<<g, 256, 0, stream>>>(h1, 512, dec_w2, dec_b2, h2); }
    { dim3 g(4, 128);
      rev3_k<<<g, 256, 0, stream>>>(h2, dec_w3, dec_b3, dmat, actions, it); }
  }

  // ---- combined clf over mgd rows (1920) + final d[:, :16] rows (2048) ----
  gemm(1, dmat, 0, tab_clf, 1, clf_w1, clf_b1, h1clf, 3968, 512, 512, 0, 1, 512, 0);
  gemm(1, h1clf, 512, nullptr, 0, clf_w2, clf_b2, h2clf, 3968, 512, 512, 0, 1, 512, 0);
  rowdot2_k<<<992, 256, 0, stream>>>(h2clf, 512, clf_w3, clf_b3, 512, out, scat_clf);

  // ---- recon = d[:, :16] @ unlift_w + unlift_b ----
  gemm(0, dmat, 0, tab_tok16, 1, unlift_w, unlift_b, recon, 2048, 512, 1024,
       0, 16, 16384, 1024);

  // ---- reward normalization, reinf, per-batch losses ----
  finalize_k<<<1, 256, 0, stream>>>(rew, lp, sl, ent,
                                    out + SL_OFF, out + ENT_OFF, out + REINF_OFF);
}